// Round 4
// baseline (1236.319 us; speedup 1.0000x reference)
//
#include <hip/hip_runtime.h>
#include <math.h>

// Dims fixed by setup_inputs: d_model=1024, d_inner=2048, d_state=16,
// d_conv=4, dt_rank=64, B=2, L=1024. Tokens T = 2048.
#define DM 1024
#define DI 2048
#define DS 16
#define DTR 64
#define NB 2
#define LL 1024
#define TT (NB*LL)
#define SCH 32            // scan chunk length -> 512 chunk-blocks
#define NCH (LL/SCH)      // 32 chunks per sequence
#define KP3 16            // gemm3 split-K planes (512 units)
#define NBLK 512          // persistent grid: 2 blocks/CU, co-resident by launch_bounds

typedef unsigned short u16;
typedef __attribute__((ext_vector_type(8))) short bf16x8;
typedef __attribute__((ext_vector_type(4))) float f32x4;

#define LOG2E 1.4426950408889634f

__device__ inline u16 f2bf(float f) {   // RNE f32->bf16
  union { float f; unsigned u; } c; c.f = f;
  unsigned u = c.u;
  return (u16)((u + 0x7fffu + ((u >> 16) & 1u)) >> 16);
}
__device__ inline float bf2f(u16 u) {
  union { unsigned u; float f; } c; c.u = ((unsigned)u) << 16;
  return c.f;
}

// order-preserving f32 <-> u32 key (for atomicMin-based global min)
__device__ inline unsigned fkey(float f) {
  union { float f; unsigned u; } c; c.f = f;
  return (c.u & 0x80000000u) ? ~c.u : (c.u | 0x80000000u);
}
__device__ inline float funkey(unsigned k) {
  union { unsigned u; float f; } c;
  c.u = (k & 0x80000000u) ? (k & 0x7fffffffu) : ~k;
  return c.f;
}

#define GLDS16(g, l) __builtin_amdgcn_global_load_lds( \
    (const __attribute__((address_space(1))) unsigned int*)(g), \
    (__attribute__((address_space(3))) unsigned int*)(l), 16, 0, 0)

// ---------------------------------------------------------------------------
// Hand-rolled grid barrier: generation counter in workspace (bar[0]=cnt,
// bar[1]=gen), device-scope atomics. All NBLK blocks must be co-resident
// (enforced by __launch_bounds__(256,2): VGPR<=256, LDS 16KB -> 2 blocks/CU).
// Spin has a poll cap so a surprise turns into a wrong answer, not a hang.
// ---------------------------------------------------------------------------
__device__ inline void gridbar(unsigned* bar) {
  __threadfence();            // release this thread's global writes (agent scope)
  __syncthreads();
  if (threadIdx.x == 0) {
    unsigned g = __hip_atomic_load(&bar[1], __ATOMIC_RELAXED, __HIP_MEMORY_SCOPE_AGENT);
    unsigned a = __hip_atomic_fetch_add(&bar[0], 1u, __ATOMIC_ACQ_REL, __HIP_MEMORY_SCOPE_AGENT);
    if (a == NBLK - 1) {
      __hip_atomic_store(&bar[0], 0u, __ATOMIC_RELAXED, __HIP_MEMORY_SCOPE_AGENT);
      __hip_atomic_fetch_add(&bar[1], 1u, __ATOMIC_RELEASE, __HIP_MEMORY_SCOPE_AGENT);
    } else {
      long spins = 0;
      while (__hip_atomic_load(&bar[1], __ATOMIC_ACQUIRE, __HIP_MEMORY_SCOPE_AGENT) == g) {
        __builtin_amdgcn_s_sleep(2);
        if (++spins > 100000000L) break;   // escape hatch: fail, don't hang
      }
    }
  }
  __syncthreads();
}

struct Params {
  const float *hs, *win, *conv_w, *conv_b, *wx, *wdt, *dt_bias, *wout, *A_log, *Dp;
  float *out;
  u16 *hs_bf, *win_bf, *wout_bf, *wx_bf, *wdt_bf;
  u16 *xz_bf, *xcv_bf, *dlt_bf, *dtraw_bf, *ybf;
  float *xdb, *hend, *Ssum;
  unsigned *betakey;
  unsigned *bar;
};

// ---------------------------------------------------------------------------
// bf16 MFMA GEMM tile (device fn): C[M,N] = A[M,K] @ B[N,K]^T, lda=ldb=K.
// bx/by/bz replace blockIdx; koff = bz*kpb.
// EPI=1: clip(softplus(v+bias[col]),1e-4,20).
// OB=1: bf16 store. OB=2: fp32 atomicAdd; if CGd>0 only cols<CGd, ldc=CGd.
// ---------------------------------------------------------------------------
template<int BM, int BN, int EPI, int OB, int CGd>
__device__ void gemm_tile(const u16* __restrict__ A, const u16* __restrict__ B,
                          void* __restrict__ Cv, int M, int N, int K, int kpb,
                          const float* __restrict__ bias,
                          int bx, int by, int bz, u16* sm) {
  constexpr int WAVES_M = BM / 64;
  constexpr int WAVES_N = 4 / WAVES_M;
  constexpr int WTM = 4;
  constexpr int WTN = BN / (WAVES_N * 16);
  constexpr int ASLABS = BM / 16;
  constexpr int SLABS = (BM + BN) / 16;
  constexpr int SPW = SLABS / 4;
  u16* As = sm;
  u16* Bs = sm + BM * 32;
  const int tid = threadIdx.x;
  const int wave = tid >> 6;
  const int lane = tid & 63;
  const int bm = by * BM;
  const int bn = bx * BN;
  const int wm = (wave / WAVES_N) * 64;
  const int wn = (wave % WAVES_N) * (WTN * 16);
  const int r4 = lane >> 2;
  const int kc = (lane & 3) * 8;
  const int fr = lane & 15;
  const int fq = lane >> 4;
  const int koff = bz * kpb;
  float* C = (float*)Cv;
  u16* C16 = (u16*)Cv;

  f32x4 acc[WTM][WTN];
#pragma unroll
  for (int i = 0; i < WTM; ++i)
#pragma unroll
    for (int j = 0; j < WTN; ++j) acc[i][j] = (f32x4){0.f, 0.f, 0.f, 0.f};

  for (int k0 = koff; k0 < koff + kpb; k0 += 32) {
#pragma unroll
    for (int s = wave * SPW; s < (wave + 1) * SPW; ++s) {
      if (s < ASLABS) {
        int row = s * 16 + r4;
        GLDS16(A + (size_t)(bm + row) * K + k0 + kc, &As[s * 512]);
      } else {
        int row = (s - ASLABS) * 16 + r4;
        GLDS16(B + (size_t)(bn + row) * K + k0 + kc, &Bs[(s - ASLABS) * 512]);
      }
    }
    __syncthreads();
    bf16x8 af[WTM], bf[WTN];
#pragma unroll
    for (int i = 0; i < WTM; ++i)
      af[i] = *(const bf16x8*)&As[(wm + 16 * i + fr) * 32 + fq * 8];
#pragma unroll
    for (int j = 0; j < WTN; ++j)
      bf[j] = *(const bf16x8*)&Bs[(wn + 16 * j + fr) * 32 + fq * 8];
#pragma unroll
    for (int i = 0; i < WTM; ++i)
#pragma unroll
      for (int j = 0; j < WTN; ++j)
        acc[i][j] = __builtin_amdgcn_mfma_f32_16x16x32_bf16(af[i], bf[j], acc[i][j], 0, 0, 0);
    __syncthreads();
  }

#pragma unroll
  for (int i = 0; i < WTM; ++i) {
    int row0 = bm + wm + 16 * i + fq * 4;
#pragma unroll
    for (int j = 0; j < WTN; ++j) {
      int col = bn + wn + 16 * j + fr;
#pragma unroll
      for (int r = 0; r < 4; ++r) {
        float v = acc[i][j][r];
        if (EPI == 1) {
          v += bias[col];
          float sp = (v > 20.0f) ? v : log1pf(expf(v));
          v = fminf(fmaxf(sp, 1e-4f), 20.0f);
        }
        if (OB == 1) {
          C16[(size_t)(row0 + r) * N + col] = f2bf(v);
        } else {  // OB == 2
          if (CGd == 0 || col < CGd) {
            const int ldc = (CGd > 0) ? CGd : N;
            atomicAdd(&C[(size_t)(row0 + r) * ldc + col], v);
          }
        }
      }
    }
  }
}

// ---------------------------------------------------------------------------
// The whole op as ONE persistent kernel, 512 blocks x 256 threads (2/CU).
// Stage bodies identical to the proven round-2 multi-kernel version; a
// hand-rolled workspace grid-barrier replaces the 9 dispatch boundaries.
// ---------------------------------------------------------------------------
__global__ __launch_bounds__(256, 2) void mega(Params p) {
  __shared__ __align__(16) u16 smem[(128 + 128) * 32];   // 16 KB, reused per stage
  const int bid = blockIdx.x;
  const int tid = threadIdx.x;

  // ---- stage 0: bf16 casts + zero xdb/out + betakey init -----------------
  for (int gid = bid * 256 + tid; gid < 2768896; gid += NBLK * 256) {
    if (gid == 0) p.betakey[0] = 0xFFFFFFFFu;
    const float* src; u16* dst; int off;
    if (gid < 524288)       { src = p.hs;   dst = p.hs_bf;   off = gid; }
    else if (gid < 1572864) { src = p.win;  dst = p.win_bf;  off = gid - 524288; }
    else if (gid < 2097152) { src = p.wout; dst = p.wout_bf; off = gid - 1572864; }
    else if (gid < 2146304) { src = p.wx;   dst = p.wx_bf;   off = gid - 2097152; }
    else if (gid < 2179072) { src = p.wdt;  dst = p.wdt_bf;  off = gid - 2146304; }
    else if (gid < 2195456) {  // zero-fill wx_bf rows 96..127
      ushort4 z4 = {0, 0, 0, 0};
      ((ushort4*)p.wx_bf)[49152 + gid - 2179072] = z4;
      continue;
    } else if (gid < 2244608) {  // zero xdb (atomic target)
      float4 z = {0.f, 0.f, 0.f, 0.f};
      ((float4*)p.xdb)[gid - 2195456] = z;
      continue;
    } else {                     // zero out (atomic target)
      float4 z = {0.f, 0.f, 0.f, 0.f};
      ((float4*)p.out)[gid - 2244608] = z;
      continue;
    }
    float4 v = ((const float4*)src)[off];
    ushort4 o;
    o.x = f2bf(v.x); o.y = f2bf(v.y); o.z = f2bf(v.z); o.w = f2bf(v.w);
    ((ushort4*)dst)[off] = o;
  }
  gridbar(p.bar);

  // ---- stage 1: xz = hs @ W_in^T (2048x4096x1024) -> bf16, 32x16 tiles ---
  gemm_tile<128, 128, 0, 1, 0>(p.hs_bf, p.win_bf, p.xz_bf, TT, 2 * DI, DM, DM,
                               nullptr, bid & 31, bid >> 5, 0, smem);
  gridbar(p.bar);

  // ---- stage 2: causal depthwise conv (k=4) + bias + SiLU ----------------
  for (int gid = bid * 256 + tid; gid < TT * 512; gid += NBLK * 256) {
    int dq = (gid & 511) * 4;
    int t = gid >> 9;
    int l = t & (LL - 1);
    float wv[4][4];
#pragma unroll
    for (int j = 0; j < 4; ++j) {
      float4 ww = *(const float4*)&p.conv_w[(dq + j) * 4];
      wv[j][0] = ww.x; wv[j][1] = ww.y; wv[j][2] = ww.z; wv[j][3] = ww.w;
    }
    float4 acc = *(const float4*)&p.conv_b[dq];
#pragma unroll
    for (int k = 0; k < 4; ++k) {
      int ll = l - 3 + k;
      if (ll < 0) continue;
      ushort4 xv = *(const ushort4*)&p.xz_bf[(size_t)(t - 3 + k) * (2 * DI) + dq];
      acc.x += bf2f(xv.x) * wv[0][k]; acc.y += bf2f(xv.y) * wv[1][k];
      acc.z += bf2f(xv.z) * wv[2][k]; acc.w += bf2f(xv.w) * wv[3][k];
    }
    acc.x /= (1.0f + expf(-acc.x)); acc.y /= (1.0f + expf(-acc.y));
    acc.z /= (1.0f + expf(-acc.z)); acc.w /= (1.0f + expf(-acc.w));
    ushort4 o;
    o.x = f2bf(acc.x); o.y = f2bf(acc.y); o.z = f2bf(acc.z); o.w = f2bf(acc.w);
    *(ushort4*)&p.xcv_bf[(size_t)t * DI + dq] = o;
  }
  gridbar(p.bar);

  // ---- stage 3: x_dbl (2048x128x2048) split-K=16, atomicAdd into xdb -----
  gemm_tile<64, 128, 0, 2, 96>(p.xcv_bf, p.wx_bf, p.xdb, TT, 128, DI, DI / KP3,
                               nullptr, 0, bid & 31, bid >> 5, smem);
  gridbar(p.bar);

  // ---- stage 4: dt_raw bf16 + global beta min (blocks 0..63) -------------
  if (bid < 64) {
    const int t0 = bid * 32;
    for (int i = tid; i < 32 * 64; i += 256) {
      int t = t0 + (i >> 6), cc = i & 63;
      p.dtraw_bf[t * 64 + cc] = f2bf(p.xdb[t * 96 + cc]);
    }
    float mn = 3.4e38f;
    for (int i = tid; i < 32 * 16; i += 256) {
      int t = t0 + (i >> 4), n = i & 15;
      mn = fminf(mn, p.xdb[t * 96 + 64 + n]);
    }
#pragma unroll
    for (int o = 32; o; o >>= 1) mn = fminf(mn, __shfl_down(mn, o));
    float* smf = (float*)smem;
    if ((tid & 63) == 0) smf[tid >> 6] = mn;
    __syncthreads();
    if (tid == 0) {
      float m = fminf(fminf(smf[0], smf[1]), fminf(smf[2], smf[3]));
      atomicMin(p.betakey, fkey(m));
    }
  }
  gridbar(p.bar);

  // ---- stage 5: delta (2048x2048x64) + softplus/clip -> bf16, 16x32 ------
  gemm_tile<64, 128, 1, 1, 0>(p.dtraw_bf, p.wdt_bf, p.dlt_bf, TT, DI, DTR, DTR,
                              p.dt_bias, bid & 15, bid >> 4, 0, smem);
  gridbar(p.bar);

  // ---- stage 6: scan pass1 (per-chunk local scan, h-end + Ssum) ----------
  {
    const int d = (bid & 7) * 256 + tid;
    const int c = (bid >> 3) & 31;
    const int b = bid >> 8;
    float (*Bsh)[16] = (float(*)[16])smem;
    const float beta = fmaxf(0.0f, -funkey(p.betakey[0]));
    const int t0 = b * LL + c * SCH;
    for (int i = tid; i < SCH * 16; i += 256) {
      int tt = i >> 4, n = i & 15;
      Bsh[tt][n] = p.xdb[(size_t)(t0 + tt) * 96 + 64 + n] + beta;
    }
    __syncthreads();
    float Av2[16];
#pragma unroll
    for (int n = 0; n < 16; ++n) Av2[n] = expf(p.A_log[d * 16 + n]) * LOG2E;
    float h[16];
#pragma unroll
    for (int n = 0; n < 16; ++n) h[n] = 0.f;
    float S = 0.f;
    for (int tt = 0; tt < SCH; ++tt) {
      int t = t0 + tt;
      float dv = bf2f(p.dlt_bf[(size_t)t * DI + d]);
      float xv = bf2f(p.xcv_bf[(size_t)t * DI + d]);
      float dx = dv * xv;
      S += dv;
#pragma unroll
      for (int n = 0; n < 16; ++n) {
        float a = __builtin_amdgcn_exp2f(-dv * Av2[n]);
        h[n] = a * h[n] + dx * Bsh[tt][n];
      }
    }
    size_t base = (((size_t)(b * NCH + c) * DI) + d) * 16;
#pragma unroll
    for (int n = 0; n < 16; ++n) p.hend[base + n] = h[n];
    p.Ssum[((size_t)(b * NCH + c) * DI) + d] = S;
  }
  gridbar(p.bar);

  // ---- stage 7: scan pass2 (inter-chunk prefix, blocks 0..255) -----------
  if (bid < 256) {
    int gid = bid * 256 + tid;   // 65536
    int n = gid & 15;
    int d = (gid >> 4) & (DI - 1);
    int b = gid >> 15;
    float Av2 = expf(p.A_log[d * 16 + n]) * LOG2E;
    float H = 0.f;
    for (int c = 0; c < NCH; ++c) {
      size_t cb = ((size_t)(b * NCH + c) * DI) + d;
      float hl = p.hend[cb * 16 + n];
      float pr = __builtin_amdgcn_exp2f(-Av2 * p.Ssum[cb]);
      p.hend[cb * 16 + n] = H;
      H = pr * H + hl;
    }
  }
  gridbar(p.bar);

  // ---- stage 8: scan pass3 (rescan with h-start, y + gate -> ybf) --------
  {
    const int d = (bid & 7) * 256 + tid;
    const int c = (bid >> 3) & 31;
    const int b = bid >> 8;
    float (*Bsh)[16] = (float(*)[16])smem;
    float (*Csh)[16] = Bsh + SCH;
    const float beta = fmaxf(0.0f, -funkey(p.betakey[0]));
    const int t0 = b * LL + c * SCH;
    for (int i = tid; i < SCH * 16; i += 256) {
      int tt = i >> 4, n = i & 15;
      size_t row = (size_t)(t0 + tt) * 96;
      Bsh[tt][n] = p.xdb[row + 64 + n] + beta;
      Csh[tt][n] = p.xdb[row + 80 + n];
    }
    __syncthreads();
    float Av2[16];
#pragma unroll
    for (int n = 0; n < 16; ++n) Av2[n] = expf(p.A_log[d * 16 + n]) * LOG2E;
    float h[16];
    size_t base = (((size_t)(b * NCH + c) * DI) + d) * 16;
#pragma unroll
    for (int n = 0; n < 16; ++n) h[n] = p.hend[base + n];
    const float Dd = p.Dp[d];
    for (int tt = 0; tt < SCH; ++tt) {
      int t = t0 + tt;
      float dv = bf2f(p.dlt_bf[(size_t)t * DI + d]);
      float xv = bf2f(p.xcv_bf[(size_t)t * DI + d]);
      float dx = dv * xv;
      float yv = 0.f;
#pragma unroll
      for (int n = 0; n < 16; ++n) {
        float a = __builtin_amdgcn_exp2f(-dv * Av2[n]);
        h[n] = a * h[n] + dx * Bsh[tt][n];
        yv += h[n] * Csh[tt][n];
      }
      float zv = bf2f(p.xz_bf[(size_t)t * (2 * DI) + DI + d]);
      float outv = (yv + xv * Dd) * (zv / (1.0f + expf(-zv)));
      p.ybf[(size_t)t * DI + d] = f2bf(outv);
    }
  }
  gridbar(p.bar);

  // ---- stage 9: out = y @ W_out^T (2048x1024x2048) split-K=4 atomic ------
  gemm_tile<128, 128, 0, 2, 0>(p.ybf, p.wout_bf, p.out, TT, DM, DI, DI / 4,
                               nullptr, bid & 7, (bid >> 3) & 15, bid >> 7, smem);
}

extern "C" void kernel_launch(void* const* d_in, const int* in_sizes, int n_in,
                              void* d_out, int out_size, void* d_ws, size_t ws_size,
                              hipStream_t stream) {
  float* ws       = (float*)d_ws;
  float* xz_bfR   = ws;                                  // 4,194,304 f
  float* xcv_bfR  = xz_bfR + (size_t)TT * 2 * DI / 2;    // 2,097,152 f
  float* xdb      = xcv_bfR + (size_t)TT * DI / 2;       //   196,608 f
  float* dlt_bfR  = xdb + (size_t)TT * 96;               // 2,097,152 f
  float* betab    = dlt_bfR + (size_t)TT * DI / 2;       //        64 f
  float* hend     = betab + 64;                          // 2,097,152 f
  float* Ssum     = hend + (size_t)NB * NCH * DI * 16;   //   131,072 f
  float* hs_bfR   = Ssum + (size_t)NB * NCH * DI;        // 1,048,576 f
  float* win_bfR  = hs_bfR + (size_t)TT * DM / 2;        // 2,097,152 f
  float* wout_bfR = win_bfR + (size_t)2 * DI * DM / 2;   // 1,048,576 f
  float* wx_bfR   = wout_bfR + (size_t)DM * DI / 2;      //   131,072 f
  float* wdt_bfR  = wx_bfR + 131072;                     //    65,536 f
  float* dtraw_bfR = wdt_bfR + 65536;                    //    65,536 f
  float* barR     = dtraw_bfR + 65536;                   //        16 f

  Params p;
  p.hs      = (const float*)d_in[0];
  p.win     = (const float*)d_in[1];
  p.conv_w  = (const float*)d_in[2];
  p.conv_b  = (const float*)d_in[3];
  p.wx      = (const float*)d_in[4];
  p.wdt     = (const float*)d_in[5];
  p.dt_bias = (const float*)d_in[6];
  p.wout    = (const float*)d_in[7];
  p.A_log   = (const float*)d_in[8];
  p.Dp      = (const float*)d_in[9];
  p.out     = (float*)d_out;
  p.hs_bf   = (u16*)hs_bfR;
  p.win_bf  = (u16*)win_bfR;
  p.wout_bf = (u16*)wout_bfR;
  p.wx_bf   = (u16*)wx_bfR;
  p.wdt_bf  = (u16*)wdt_bfR;
  p.xz_bf   = (u16*)xz_bfR;
  p.xcv_bf  = (u16*)xcv_bfR;
  p.dlt_bf  = (u16*)dlt_bfR;
  p.dtraw_bf = (u16*)dtraw_bfR;
  p.ybf     = (u16*)win_bfR;     // aliases win_bf (dead after stage 1)
  p.xdb     = xdb;
  p.hend    = hend;
  p.Ssum    = Ssum;
  p.betakey = (unsigned*)betab;
  p.bar     = (unsigned*)barR;

  // zero the barrier counters each launch (workspace is re-poisoned between
  // iterations); capturable stream op, ordered before the kernel.
  hipMemsetAsync(barR, 0, 2 * sizeof(unsigned), stream);
  mega<<<dim3(NBLK), dim3(256), 0, stream>>>(p);
}

// Round 5
// 433.576 us; speedup vs baseline: 2.8514x; 2.8514x over previous
//
#include <hip/hip_runtime.h>
#include <math.h>

// Dims fixed by setup_inputs: d_model=1024, d_inner=2048, d_state=16,
// d_conv=4, dt_rank=64, B=2, L=1024. Tokens T = 2048.
#define DM 1024
#define DI 2048
#define DS 16
#define DTR 64
#define NB 2
#define LL 1024
#define TT (NB*LL)
#define SCH 32            // scan chunk length -> 512 chunk-blocks
#define NCH (LL/SCH)      // 32 chunks per sequence
#define KP3 16            // gemm3 split-K planes (512 units)
#define NBLK 512          // persistent grid: 2 blocks/CU, co-resident by launch_bounds
#define BAR_GROUPS 64
#define BAR_GSZ (NBLK / BAR_GROUPS)   // 8

typedef unsigned short u16;
typedef __attribute__((ext_vector_type(8))) short bf16x8;
typedef __attribute__((ext_vector_type(4))) float f32x4;

#define LOG2E 1.4426950408889634f

__device__ inline u16 f2bf(float f) {   // RNE f32->bf16
  union { float f; unsigned u; } c; c.f = f;
  unsigned u = c.u;
  return (u16)((u + 0x7fffu + ((u >> 16) & 1u)) >> 16);
}
__device__ inline float bf2f(u16 u) {
  union { unsigned u; float f; } c; c.u = ((unsigned)u) << 16;
  return c.f;
}

// order-preserving f32 <-> u32 key (for atomicMin-based global min)
__device__ inline unsigned fkey(float f) {
  union { float f; unsigned u; } c; c.f = f;
  return (c.u & 0x80000000u) ? ~c.u : (c.u | 0x80000000u);
}
__device__ inline float funkey(unsigned k) {
  union { unsigned u; float f; } c;
  c.u = (k & 0x80000000u) ? (k & 0x7fffffffu) : ~k;
  return c.f;
}

#define GLDS16(g, l) __builtin_amdgcn_global_load_lds( \
    (const __attribute__((address_space(1))) unsigned int*)(g), \
    (__attribute__((address_space(3))) unsigned int*)(l), 16, 0, 0)

// ---------------------------------------------------------------------------
// Grid barrier, v2. Layout in bar[]:
//   bar[g*16]  g=0..63 : per-group arrival counters (separate cache lines)
//   bar[1024]          : global (group-leader) counter
//   bar[1040]          : generation
// Protocol per block (thread 0 only):
//   release fence (one buffer_wbl2)  ->  relaxed group fetch_add
//   group leader: relaxed global fetch_add; last leader bumps gen (relaxed)
//   ALL: poll gen with RELAXED loads (no cache-maintenance per poll!)
//   one acquire fence (one buffer_inv) after gen observed.
// Round-4 failure mode fixed: acquire-per-poll emitted an L2 invalidate per
// iteration from 511 blocks -> ~110 us/barrier. Now exactly one inv/block.
// ---------------------------------------------------------------------------
__device__ inline void gridbar(unsigned* bar) {
  __syncthreads();   // compiler emits s_waitcnt vmcnt(0) -> block stores in L2
  if (threadIdx.x == 0) {
    __builtin_amdgcn_fence(__ATOMIC_RELEASE, "agent");   // flush this XCD L2
    unsigned* gen = &bar[1040];
    unsigned g = __hip_atomic_load(gen, __ATOMIC_RELAXED, __HIP_MEMORY_SCOPE_AGENT);
    unsigned* grp = &bar[(blockIdx.x & (BAR_GROUPS - 1)) * 16];
    unsigned a = __hip_atomic_fetch_add(grp, 1u, __ATOMIC_RELAXED, __HIP_MEMORY_SCOPE_AGENT);
    if (a == BAR_GSZ - 1) {
      __hip_atomic_store(grp, 0u, __ATOMIC_RELAXED, __HIP_MEMORY_SCOPE_AGENT);
      unsigned b = __hip_atomic_fetch_add(&bar[1024], 1u, __ATOMIC_RELAXED, __HIP_MEMORY_SCOPE_AGENT);
      if (b == BAR_GROUPS - 1) {
        __hip_atomic_store(&bar[1024], 0u, __ATOMIC_RELAXED, __HIP_MEMORY_SCOPE_AGENT);
        __hip_atomic_store(gen, g + 1u, __ATOMIC_RELAXED, __HIP_MEMORY_SCOPE_AGENT);
      }
    }
    long spins = 0;
    while (__hip_atomic_load(gen, __ATOMIC_RELAXED, __HIP_MEMORY_SCOPE_AGENT) == g) {
      __builtin_amdgcn_s_sleep(8);
      if (++spins > 5000000L) break;   // escape hatch: fail, don't hang
    }
    __builtin_amdgcn_fence(__ATOMIC_ACQUIRE, "agent");   // one inv, post-wait
  }
  __syncthreads();
}

struct Params {
  const float *hs, *win, *conv_w, *conv_b, *wx, *wdt, *dt_bias, *wout, *A_log, *Dp;
  float *out;
  u16 *hs_bf, *win_bf, *wout_bf, *wx_bf, *wdt_bf;
  u16 *xz_bf, *xcv_bf, *dlt_bf, *dtraw_bf, *ybf;
  float *xdb, *hend, *Ssum;
  unsigned *betakey;
  unsigned *bar;
};

// ---------------------------------------------------------------------------
// bf16 MFMA GEMM tile (device fn): C[M,N] = A[M,K] @ B[N,K]^T, lda=ldb=K.
// bx/by/bz replace blockIdx; koff = bz*kpb.
// EPI=1: clip(softplus(v+bias[col]),1e-4,20).
// OB=1: bf16 store. OB=2: fp32 atomicAdd; if CGd>0 only cols<CGd, ldc=CGd.
// ---------------------------------------------------------------------------
template<int BM, int BN, int EPI, int OB, int CGd>
__device__ void gemm_tile(const u16* __restrict__ A, const u16* __restrict__ B,
                          void* __restrict__ Cv, int M, int N, int K, int kpb,
                          const float* __restrict__ bias,
                          int bx, int by, int bz, u16* sm) {
  constexpr int WAVES_M = BM / 64;
  constexpr int WAVES_N = 4 / WAVES_M;
  constexpr int WTM = 4;
  constexpr int WTN = BN / (WAVES_N * 16);
  constexpr int ASLABS = BM / 16;
  constexpr int SLABS = (BM + BN) / 16;
  constexpr int SPW = SLABS / 4;
  u16* As = sm;
  u16* Bs = sm + BM * 32;
  const int tid = threadIdx.x;
  const int wave = tid >> 6;
  const int lane = tid & 63;
  const int bm = by * BM;
  const int bn = bx * BN;
  const int wm = (wave / WAVES_N) * 64;
  const int wn = (wave % WAVES_N) * (WTN * 16);
  const int r4 = lane >> 2;
  const int kc = (lane & 3) * 8;
  const int fr = lane & 15;
  const int fq = lane >> 4;
  const int koff = bz * kpb;
  float* C = (float*)Cv;
  u16* C16 = (u16*)Cv;

  f32x4 acc[WTM][WTN];
#pragma unroll
  for (int i = 0; i < WTM; ++i)
#pragma unroll
    for (int j = 0; j < WTN; ++j) acc[i][j] = (f32x4){0.f, 0.f, 0.f, 0.f};

  for (int k0 = koff; k0 < koff + kpb; k0 += 32) {
#pragma unroll
    for (int s = wave * SPW; s < (wave + 1) * SPW; ++s) {
      if (s < ASLABS) {
        int row = s * 16 + r4;
        GLDS16(A + (size_t)(bm + row) * K + k0 + kc, &As[s * 512]);
      } else {
        int row = (s - ASLABS) * 16 + r4;
        GLDS16(B + (size_t)(bn + row) * K + k0 + kc, &Bs[(s - ASLABS) * 512]);
      }
    }
    __syncthreads();
    bf16x8 af[WTM], bf[WTN];
#pragma unroll
    for (int i = 0; i < WTM; ++i)
      af[i] = *(const bf16x8*)&As[(wm + 16 * i + fr) * 32 + fq * 8];
#pragma unroll
    for (int j = 0; j < WTN; ++j)
      bf[j] = *(const bf16x8*)&Bs[(wn + 16 * j + fr) * 32 + fq * 8];
#pragma unroll
    for (int i = 0; i < WTM; ++i)
#pragma unroll
      for (int j = 0; j < WTN; ++j)
        acc[i][j] = __builtin_amdgcn_mfma_f32_16x16x32_bf16(af[i], bf[j], acc[i][j], 0, 0, 0);
    __syncthreads();
  }

#pragma unroll
  for (int i = 0; i < WTM; ++i) {
    int row0 = bm + wm + 16 * i + fq * 4;
#pragma unroll
    for (int j = 0; j < WTN; ++j) {
      int col = bn + wn + 16 * j + fr;
#pragma unroll
      for (int r = 0; r < 4; ++r) {
        float v = acc[i][j][r];
        if (EPI == 1) {
          v += bias[col];
          float sp = (v > 20.0f) ? v : log1pf(expf(v));
          v = fminf(fmaxf(sp, 1e-4f), 20.0f);
        }
        if (OB == 1) {
          C16[(size_t)(row0 + r) * N + col] = f2bf(v);
        } else {  // OB == 2
          if (CGd == 0 || col < CGd) {
            const int ldc = (CGd > 0) ? CGd : N;
            atomicAdd(&C[(size_t)(row0 + r) * ldc + col], v);
          }
        }
      }
    }
  }
}

// ---------------------------------------------------------------------------
// The whole op as ONE persistent kernel, 512 blocks x 256 threads (2/CU).
// Stage bodies identical to the passing round-4 version; only the barrier
// protocol changed (relaxed polls, single fences, tree arrival).
// ---------------------------------------------------------------------------
__global__ __launch_bounds__(256, 2) void mega(Params p) {
  __shared__ __align__(16) u16 smem[(128 + 128) * 32];   // 16 KB, reused per stage
  const int bid = blockIdx.x;
  const int tid = threadIdx.x;

  // ---- stage 0: bf16 casts + zero xdb/out + betakey init -----------------
  for (int gid = bid * 256 + tid; gid < 2768896; gid += NBLK * 256) {
    if (gid == 0) p.betakey[0] = 0xFFFFFFFFu;
    const float* src; u16* dst; int off;
    if (gid < 524288)       { src = p.hs;   dst = p.hs_bf;   off = gid; }
    else if (gid < 1572864) { src = p.win;  dst = p.win_bf;  off = gid - 524288; }
    else if (gid < 2097152) { src = p.wout; dst = p.wout_bf; off = gid - 1572864; }
    else if (gid < 2146304) { src = p.wx;   dst = p.wx_bf;   off = gid - 2097152; }
    else if (gid < 2179072) { src = p.wdt;  dst = p.wdt_bf;  off = gid - 2146304; }
    else if (gid < 2195456) {  // zero-fill wx_bf rows 96..127
      ushort4 z4 = {0, 0, 0, 0};
      ((ushort4*)p.wx_bf)[49152 + gid - 2179072] = z4;
      continue;
    } else if (gid < 2244608) {  // zero xdb (atomic target)
      float4 z = {0.f, 0.f, 0.f, 0.f};
      ((float4*)p.xdb)[gid - 2195456] = z;
      continue;
    } else {                     // zero out (atomic target)
      float4 z = {0.f, 0.f, 0.f, 0.f};
      ((float4*)p.out)[gid - 2244608] = z;
      continue;
    }
    float4 v = ((const float4*)src)[off];
    ushort4 o;
    o.x = f2bf(v.x); o.y = f2bf(v.y); o.z = f2bf(v.z); o.w = f2bf(v.w);
    ((ushort4*)dst)[off] = o;
  }
  gridbar(p.bar);

  // ---- stage 1: xz = hs @ W_in^T (2048x4096x1024) -> bf16, 32x16 tiles ---
  gemm_tile<128, 128, 0, 1, 0>(p.hs_bf, p.win_bf, p.xz_bf, TT, 2 * DI, DM, DM,
                               nullptr, bid & 31, bid >> 5, 0, smem);
  gridbar(p.bar);

  // ---- stage 2: causal depthwise conv (k=4) + bias + SiLU ----------------
  for (int gid = bid * 256 + tid; gid < TT * 512; gid += NBLK * 256) {
    int dq = (gid & 511) * 4;
    int t = gid >> 9;
    int l = t & (LL - 1);
    float wv[4][4];
#pragma unroll
    for (int j = 0; j < 4; ++j) {
      float4 ww = *(const float4*)&p.conv_w[(dq + j) * 4];
      wv[j][0] = ww.x; wv[j][1] = ww.y; wv[j][2] = ww.z; wv[j][3] = ww.w;
    }
    float4 acc = *(const float4*)&p.conv_b[dq];
#pragma unroll
    for (int k = 0; k < 4; ++k) {
      int ll = l - 3 + k;
      if (ll < 0) continue;
      ushort4 xv = *(const ushort4*)&p.xz_bf[(size_t)(t - 3 + k) * (2 * DI) + dq];
      acc.x += bf2f(xv.x) * wv[0][k]; acc.y += bf2f(xv.y) * wv[1][k];
      acc.z += bf2f(xv.z) * wv[2][k]; acc.w += bf2f(xv.w) * wv[3][k];
    }
    acc.x /= (1.0f + expf(-acc.x)); acc.y /= (1.0f + expf(-acc.y));
    acc.z /= (1.0f + expf(-acc.z)); acc.w /= (1.0f + expf(-acc.w));
    ushort4 o;
    o.x = f2bf(acc.x); o.y = f2bf(acc.y); o.z = f2bf(acc.z); o.w = f2bf(acc.w);
    *(ushort4*)&p.xcv_bf[(size_t)t * DI + dq] = o;
  }
  gridbar(p.bar);

  // ---- stage 3: x_dbl (2048x128x2048) split-K=16, atomicAdd into xdb -----
  gemm_tile<64, 128, 0, 2, 96>(p.xcv_bf, p.wx_bf, p.xdb, TT, 128, DI, DI / KP3,
                               nullptr, 0, bid & 31, bid >> 5, smem);
  gridbar(p.bar);

  // ---- stage 4: dt_raw bf16 + global beta min (blocks 0..63) -------------
  if (bid < 64) {
    const int t0 = bid * 32;
    for (int i = tid; i < 32 * 64; i += 256) {
      int t = t0 + (i >> 6), cc = i & 63;
      p.dtraw_bf[t * 64 + cc] = f2bf(p.xdb[t * 96 + cc]);
    }
    float mn = 3.4e38f;
    for (int i = tid; i < 32 * 16; i += 256) {
      int t = t0 + (i >> 4), n = i & 15;
      mn = fminf(mn, p.xdb[t * 96 + 64 + n]);
    }
#pragma unroll
    for (int o = 32; o; o >>= 1) mn = fminf(mn, __shfl_down(mn, o));
    float* smf = (float*)smem;
    if ((tid & 63) == 0) smf[tid >> 6] = mn;
    __syncthreads();
    if (tid == 0) {
      float m = fminf(fminf(smf[0], smf[1]), fminf(smf[2], smf[3]));
      atomicMin(p.betakey, fkey(m));
    }
  }
  gridbar(p.bar);

  // ---- stage 5: delta (2048x2048x64) + softplus/clip -> bf16, 16x32 ------
  gemm_tile<64, 128, 1, 1, 0>(p.dtraw_bf, p.wdt_bf, p.dlt_bf, TT, DI, DTR, DTR,
                              p.dt_bias, bid & 15, bid >> 4, 0, smem);
  gridbar(p.bar);

  // ---- stage 6: scan pass1 (per-chunk local scan, h-end + Ssum) ----------
  {
    const int d = (bid & 7) * 256 + tid;
    const int c = (bid >> 3) & 31;
    const int b = bid >> 8;
    float (*Bsh)[16] = (float(*)[16])smem;
    const float beta = fmaxf(0.0f, -funkey(p.betakey[0]));
    const int t0 = b * LL + c * SCH;
    for (int i = tid; i < SCH * 16; i += 256) {
      int tt = i >> 4, n = i & 15;
      Bsh[tt][n] = p.xdb[(size_t)(t0 + tt) * 96 + 64 + n] + beta;
    }
    __syncthreads();
    float Av2[16];
#pragma unroll
    for (int n = 0; n < 16; ++n) Av2[n] = expf(p.A_log[d * 16 + n]) * LOG2E;
    float h[16];
#pragma unroll
    for (int n = 0; n < 16; ++n) h[n] = 0.f;
    float S = 0.f;
    for (int tt = 0; tt < SCH; ++tt) {
      int t = t0 + tt;
      float dv = bf2f(p.dlt_bf[(size_t)t * DI + d]);
      float xv = bf2f(p.xcv_bf[(size_t)t * DI + d]);
      float dx = dv * xv;
      S += dv;
#pragma unroll
      for (int n = 0; n < 16; ++n) {
        float a = __builtin_amdgcn_exp2f(-dv * Av2[n]);
        h[n] = a * h[n] + dx * Bsh[tt][n];
      }
    }
    size_t base = (((size_t)(b * NCH + c) * DI) + d) * 16;
#pragma unroll
    for (int n = 0; n < 16; ++n) p.hend[base + n] = h[n];
    p.Ssum[((size_t)(b * NCH + c) * DI) + d] = S;
  }
  gridbar(p.bar);

  // ---- stage 7: scan pass2 (inter-chunk prefix, blocks 0..255) -----------
  if (bid < 256) {
    int gid = bid * 256 + tid;   // 65536
    int n = gid & 15;
    int d = (gid >> 4) & (DI - 1);
    int b = gid >> 15;
    float Av2 = expf(p.A_log[d * 16 + n]) * LOG2E;
    float H = 0.f;
    for (int c = 0; c < NCH; ++c) {
      size_t cb = ((size_t)(b * NCH + c) * DI) + d;
      float hl = p.hend[cb * 16 + n];
      float pr = __builtin_amdgcn_exp2f(-Av2 * p.Ssum[cb]);
      p.hend[cb * 16 + n] = H;
      H = pr * H + hl;
    }
  }
  gridbar(p.bar);

  // ---- stage 8: scan pass3 (rescan with h-start, y + gate -> ybf) --------
  {
    const int d = (bid & 7) * 256 + tid;
    const int c = (bid >> 3) & 31;
    const int b = bid >> 8;
    float (*Bsh)[16] = (float(*)[16])smem;
    float (*Csh)[16] = Bsh + SCH;
    const float beta = fmaxf(0.0f, -funkey(p.betakey[0]));
    const int t0 = b * LL + c * SCH;
    for (int i = tid; i < SCH * 16; i += 256) {
      int tt = i >> 4, n = i & 15;
      size_t row = (size_t)(t0 + tt) * 96;
      Bsh[tt][n] = p.xdb[row + 64 + n] + beta;
      Csh[tt][n] = p.xdb[row + 80 + n];
    }
    __syncthreads();
    float Av2[16];
#pragma unroll
    for (int n = 0; n < 16; ++n) Av2[n] = expf(p.A_log[d * 16 + n]) * LOG2E;
    float h[16];
    size_t base = (((size_t)(b * NCH + c) * DI) + d) * 16;
#pragma unroll
    for (int n = 0; n < 16; ++n) h[n] = p.hend[base + n];
    const float Dd = p.Dp[d];
    for (int tt = 0; tt < SCH; ++tt) {
      int t = t0 + tt;
      float dv = bf2f(p.dlt_bf[(size_t)t * DI + d]);
      float xv = bf2f(p.xcv_bf[(size_t)t * DI + d]);
      float dx = dv * xv;
      float yv = 0.f;
#pragma unroll
      for (int n = 0; n < 16; ++n) {
        float a = __builtin_amdgcn_exp2f(-dv * Av2[n]);
        h[n] = a * h[n] + dx * Bsh[tt][n];
        yv += h[n] * Csh[tt][n];
      }
      float zv = bf2f(p.xz_bf[(size_t)t * (2 * DI) + DI + d]);
      float outv = (yv + xv * Dd) * (zv / (1.0f + expf(-zv)));
      p.ybf[(size_t)t * DI + d] = f2bf(outv);
    }
  }
  gridbar(p.bar);

  // ---- stage 9: out = y @ W_out^T (2048x1024x2048) split-K=4 atomic ------
  gemm_tile<128, 128, 0, 2, 0>(p.ybf, p.wout_bf, p.out, TT, DM, DI, DI / 4,
                               nullptr, bid & 7, (bid >> 3) & 15, bid >> 7, smem);
}

extern "C" void kernel_launch(void* const* d_in, const int* in_sizes, int n_in,
                              void* d_out, int out_size, void* d_ws, size_t ws_size,
                              hipStream_t stream) {
  float* ws       = (float*)d_ws;
  float* xz_bfR   = ws;                                  // 4,194,304 f
  float* xcv_bfR  = xz_bfR + (size_t)TT * 2 * DI / 2;    // 2,097,152 f
  float* xdb      = xcv_bfR + (size_t)TT * DI / 2;       //   196,608 f
  float* dlt_bfR  = xdb + (size_t)TT * 96;               // 2,097,152 f
  float* betab    = dlt_bfR + (size_t)TT * DI / 2;       //        64 f
  float* hend     = betab + 64;                          // 2,097,152 f
  float* Ssum     = hend + (size_t)NB * NCH * DI * 16;   //   131,072 f
  float* hs_bfR   = Ssum + (size_t)NB * NCH * DI;        // 1,048,576 f
  float* win_bfR  = hs_bfR + (size_t)TT * DM / 2;        // 2,097,152 f
  float* wout_bfR = win_bfR + (size_t)2 * DI * DM / 2;   // 1,048,576 f
  float* wx_bfR   = wout_bfR + (size_t)DM * DI / 2;      //   131,072 f
  float* wdt_bfR  = wx_bfR + 131072;                     //    65,536 f
  float* dtraw_bfR = wdt_bfR + 65536;                    //    65,536 f
  float* barR     = dtraw_bfR + 65536;                   //     1,056 f (barrier)

  Params p;
  p.hs      = (const float*)d_in[0];
  p.win     = (const float*)d_in[1];
  p.conv_w  = (const float*)d_in[2];
  p.conv_b  = (const float*)d_in[3];
  p.wx      = (const float*)d_in[4];
  p.wdt     = (const float*)d_in[5];
  p.dt_bias = (const float*)d_in[6];
  p.wout    = (const float*)d_in[7];
  p.A_log   = (const float*)d_in[8];
  p.Dp      = (const float*)d_in[9];
  p.out     = (float*)d_out;
  p.hs_bf   = (u16*)hs_bfR;
  p.win_bf  = (u16*)win_bfR;
  p.wout_bf = (u16*)wout_bfR;
  p.wx_bf   = (u16*)wx_bfR;
  p.wdt_bf  = (u16*)wdt_bfR;
  p.xz_bf   = (u16*)xz_bfR;
  p.xcv_bf  = (u16*)xcv_bfR;
  p.dlt_bf  = (u16*)dlt_bfR;
  p.dtraw_bf = (u16*)dtraw_bfR;
  p.ybf     = (u16*)win_bfR;     // aliases win_bf (dead after stage 1)
  p.xdb     = xdb;
  p.hend    = hend;
  p.Ssum    = Ssum;
  p.betakey = (unsigned*)betab;
  p.bar     = (unsigned*)barR;

  // zero the barrier counters each launch (workspace is re-poisoned between
  // iterations); capturable stream op, ordered before the kernel.
  hipMemsetAsync(barR, 0, 1056 * sizeof(unsigned), stream);
  mega<<<dim3(NBLK), dim3(256), 0, stream>>>(p);
}

// Round 6
// 313.192 us; speedup vs baseline: 3.9475x; 1.3844x over previous
//
#include <hip/hip_runtime.h>
#include <math.h>

// Dims fixed by setup_inputs: d_model=1024, d_inner=2048, d_state=16,
// d_conv=4, dt_rank=64, B=2, L=1024. Tokens T = 2048.
#define DM 1024
#define DI 2048
#define DS 16
#define DTR 64
#define NB 2
#define LL 1024
#define TT (NB*LL)
#define SCH 32            // scan chunk length -> 512 blocks -> 2/CU
#define NCH (LL/SCH)      // 32 chunks per sequence

typedef unsigned short u16;
typedef __attribute__((ext_vector_type(8))) short bf16x8;
typedef __attribute__((ext_vector_type(4))) float f32x4;

#define LOG2E 1.4426950408889634f

__device__ inline u16 f2bf(float f) {   // RNE f32->bf16
  union { float f; unsigned u; } c; c.f = f;
  unsigned u = c.u;
  return (u16)((u + 0x7fffu + ((u >> 16) & 1u)) >> 16);
}
__device__ inline float bf2f(u16 u) {
  union { unsigned u; float f; } c; c.u = ((unsigned)u) << 16;
  return c.f;
}

// order-preserving f32 <-> u32 key (for atomicMin-based global min)
__device__ inline unsigned fkey(float f) {
  union { float f; unsigned u; } c; c.f = f;
  return (c.u & 0x80000000u) ? ~c.u : (c.u | 0x80000000u);
}
__device__ inline float funkey(unsigned k) {
  union { unsigned u; float f; } c;
  c.u = (k & 0x80000000u) ? (k & 0x7fffffffu) : ~k;
  return c.f;
}

__device__ inline bf16x8 cvt8(float4 a, float4 b) {
  bf16x8 w;
  w[0] = (short)f2bf(a.x); w[1] = (short)f2bf(a.y);
  w[2] = (short)f2bf(a.z); w[3] = (short)f2bf(a.w);
  w[4] = (short)f2bf(b.x); w[5] = (short)f2bf(b.y);
  w[6] = (short)f2bf(b.z); w[7] = (short)f2bf(b.w);
  return w;
}

#define GLDS16(g, l) __builtin_amdgcn_global_load_lds( \
    (const __attribute__((address_space(1))) unsigned int*)(g), \
    (__attribute__((address_space(3))) unsigned int*)(l), 16, 0, 0)

// ---------------------------------------------------------------------------
// bf16 MFMA GEMM: C[M,N] = A[M,K] @ B[N,K]^T.
// ASRC/BSRC: 0 = bf16 source via global_load_lds; 1 = fp32 source, reg-staged
//            (float4 x2 -> RNE cvt -> ds_write_b128, same LDS layout).
// BVAL>0: B rows >= BVAL are zero (W_x has 96 real rows, tile is 128).
// EPI=1: clip(softplus(v+bias[col]),1e-4,20).
// OB=1: bf16 store. OB=2: fp32 atomicAdd; if CGd>0 only cols<CGd, ldc=CGd.
// BMIN=1: flat blocks 0..63 first reduce min over minsrc[t*96+64..79] into
//         betakey (order-preserving key, atomicMin).
// ---------------------------------------------------------------------------
template<int BM, int BN, int EPI, int OB, int CGd, int ASRC, int BSRC,
         int BVAL, int BMIN>
__global__ __launch_bounds__(256) void gemm_k(
    const void* __restrict__ Av, const void* __restrict__ Bv,
    void* __restrict__ Cv, int M, int N, int K, int lda, int ldb, int kpb,
    const float* __restrict__ bias,
    const float* __restrict__ minsrc, unsigned* __restrict__ betakey) {
  constexpr int WAVES_M = BM / 64;
  constexpr int WAVES_N = 4 / WAVES_M;
  constexpr int WTM = 4;
  constexpr int WTN = BN / (WAVES_N * 16);
  constexpr int ASLABS = BM / 16;
  constexpr int SLABS = (BM + BN) / 16;
  constexpr int SPW = SLABS / 4;
  __shared__ u16 As[BM * 32];
  __shared__ u16 Bs[BN * 32];
  __shared__ float sm4[4];
  const int tid = threadIdx.x;
  const int wave = tid >> 6;
  const int lane = tid & 63;
  const int bm = blockIdx.y * BM;
  const int bn = blockIdx.x * BN;
  const int wm = (wave / WAVES_N) * 64;
  const int wn = (wave % WAVES_N) * (WTN * 16);
  const int r4 = lane >> 2;
  const int kc = (lane & 3) * 8;
  const int fr = lane & 15;
  const int fq = lane >> 4;
  const int koff = blockIdx.z * kpb;
  float* C = (float*)Cv;
  u16* C16 = (u16*)Cv;

  if constexpr (BMIN == 1) {   // beta-min prologue (blocks 0..63)
    int fb = blockIdx.y * gridDim.x + blockIdx.x;
    if (fb < 64) {
      const int t0 = fb * 32;
      float mn = 3.4e38f;
      for (int i = tid; i < 32 * 16; i += 256) {
        int t = t0 + (i >> 4), n = i & 15;
        mn = fminf(mn, minsrc[t * 96 + 64 + n]);
      }
#pragma unroll
      for (int o = 32; o; o >>= 1) mn = fminf(mn, __shfl_down(mn, o));
      if ((tid & 63) == 0) sm4[tid >> 6] = mn;
      __syncthreads();
      if (tid == 0)
        atomicMin(betakey, fkey(fminf(fminf(sm4[0], sm4[1]), fminf(sm4[2], sm4[3]))));
      __syncthreads();
    }
  }

  f32x4 acc[WTM][WTN];
#pragma unroll
  for (int i = 0; i < WTM; ++i)
#pragma unroll
    for (int j = 0; j < WTN; ++j) acc[i][j] = (f32x4){0.f, 0.f, 0.f, 0.f};

  for (int k0 = koff; k0 < koff + kpb; k0 += 32) {
#pragma unroll
    for (int s = wave * SPW; s < (wave + 1) * SPW; ++s) {
      if (s < ASLABS) {
        int row = s * 16 + r4;
        if constexpr (ASRC == 0) {
          GLDS16((const u16*)Av + (size_t)(bm + row) * lda + k0 + kc, &As[s * 512]);
        } else {
          const float* src = (const float*)Av + (size_t)(bm + row) * lda + k0 + kc;
          float4 v0 = *(const float4*)src;
          float4 v1 = *(const float4*)(src + 4);
          *(bf16x8*)&As[s * 512 + lane * 8] = cvt8(v0, v1);
        }
      } else {
        int bs = s - ASLABS;
        int row = bs * 16 + r4;
        if constexpr (BSRC == 0) {
          GLDS16((const u16*)Bv + (size_t)(bn + row) * ldb + k0 + kc, &Bs[bs * 512]);
        } else {
          bf16x8 w;
#pragma unroll
          for (int q = 0; q < 8; ++q) w[q] = 0;
          if (BVAL == 0 || (bn + row) < BVAL) {
            const float* src = (const float*)Bv + (size_t)(bn + row) * ldb + k0 + kc;
            float4 v0 = *(const float4*)src;
            float4 v1 = *(const float4*)(src + 4);
            w = cvt8(v0, v1);
          }
          *(bf16x8*)&Bs[bs * 512 + lane * 8] = w;
        }
      }
    }
    __syncthreads();
    bf16x8 af[WTM], bf[WTN];
#pragma unroll
    for (int i = 0; i < WTM; ++i)
      af[i] = *(const bf16x8*)&As[(wm + 16 * i + fr) * 32 + fq * 8];
#pragma unroll
    for (int j = 0; j < WTN; ++j)
      bf[j] = *(const bf16x8*)&Bs[(wn + 16 * j + fr) * 32 + fq * 8];
#pragma unroll
    for (int i = 0; i < WTM; ++i)
#pragma unroll
      for (int j = 0; j < WTN; ++j)
        acc[i][j] = __builtin_amdgcn_mfma_f32_16x16x32_bf16(af[i], bf[j], acc[i][j], 0, 0, 0);
    __syncthreads();
  }

#pragma unroll
  for (int i = 0; i < WTM; ++i) {
    int row0 = bm + wm + 16 * i + fq * 4;
#pragma unroll
    for (int j = 0; j < WTN; ++j) {
      int col = bn + wn + 16 * j + fr;
#pragma unroll
      for (int r = 0; r < 4; ++r) {
        float v = acc[i][j][r];
        if (EPI == 1) {
          v += bias[col];
          float sp = (v > 20.0f) ? v : log1pf(expf(v));
          v = fminf(fmaxf(sp, 1e-4f), 20.0f);
        }
        if (OB == 1) {
          C16[(size_t)(row0 + r) * N + col] = f2bf(v);
        } else {  // OB == 2
          if (CGd == 0 || col < CGd) {
            const int ldc = (CGd > 0) ? CGd : N;
            atomicAdd(&C[(size_t)(row0 + r) * ldc + col], v);
          }
        }
      }
    }
  }
}

// ---------------------------------------------------------------------------
// cast2: hs, W_in -> bf16; zero xdb + out (atomic targets); betakey init.
// ---------------------------------------------------------------------------
__global__ __launch_bounds__(256) void cast2(
    const float* __restrict__ hs, const float* __restrict__ win,
    u16* __restrict__ hs_bf, u16* __restrict__ win_bf,
    float* __restrict__ xdb, float* __restrict__ outz,
    unsigned* __restrict__ betakey) {
  int gid = blockIdx.x * 256 + threadIdx.x;  // 2,146,304 total
  if (gid == 0) betakey[0] = 0xFFFFFFFFu;
  const float* src; u16* dst; int off;
  if (gid < 524288)       { src = hs;  dst = hs_bf;  off = gid; }
  else if (gid < 1572864) { src = win; dst = win_bf; off = gid - 524288; }
  else if (gid < 1622016) {  // zero xdb (196,608 f)
    float4 z = {0.f, 0.f, 0.f, 0.f};
    ((float4*)xdb)[gid - 1572864] = z;
    return;
  } else {                   // zero out (2,097,152 f)
    float4 z = {0.f, 0.f, 0.f, 0.f};
    ((float4*)outz)[gid - 1622016] = z;
    return;
  }
  float4 v = ((const float4*)src)[off];
  ushort4 o;
  o.x = f2bf(v.x); o.y = f2bf(v.y); o.z = f2bf(v.z); o.w = f2bf(v.w);
  ((ushort4*)dst)[off] = o;
}

// ---------------------------------------------------------------------------
// Causal depthwise conv (k=4, pad 3) + bias + SiLU. bf16 in, bf16 out.
// ---------------------------------------------------------------------------
__global__ __launch_bounds__(256) void conv_silu4(
    const u16* __restrict__ xz, const float* __restrict__ w,
    const float* __restrict__ cb, u16* __restrict__ xc_bf) {
  int gid = blockIdx.x * 256 + threadIdx.x;  // TT*512
  int dq = (gid & 511) * 4;
  int t = gid >> 9;
  int l = t & (LL - 1);
  float wv[4][4];
#pragma unroll
  for (int j = 0; j < 4; ++j) {
    float4 ww = *(const float4*)&w[(dq + j) * 4];
    wv[j][0] = ww.x; wv[j][1] = ww.y; wv[j][2] = ww.z; wv[j][3] = ww.w;
  }
  float4 acc = *(const float4*)&cb[dq];
#pragma unroll
  for (int k = 0; k < 4; ++k) {
    int ll = l - 3 + k;
    if (ll < 0) continue;
    ushort4 xv = *(const ushort4*)&xz[(size_t)(t - 3 + k) * (2 * DI) + dq];
    acc.x += bf2f(xv.x) * wv[0][k]; acc.y += bf2f(xv.y) * wv[1][k];
    acc.z += bf2f(xv.z) * wv[2][k]; acc.w += bf2f(xv.w) * wv[3][k];
  }
  acc.x /= (1.0f + expf(-acc.x)); acc.y /= (1.0f + expf(-acc.y));
  acc.z /= (1.0f + expf(-acc.z)); acc.w /= (1.0f + expf(-acc.w));
  ushort4 o;
  o.x = f2bf(acc.x); o.y = f2bf(acc.y); o.z = f2bf(acc.z); o.w = f2bf(acc.w);
  *(ushort4*)&xc_bf[(size_t)t * DI + dq] = o;
}

// ---------------------------------------------------------------------------
// scan pass1: per-chunk local scan -> hend (local), Ssum.
// ---------------------------------------------------------------------------
__global__ __launch_bounds__(256) void scan_pass1(
    const u16* __restrict__ delta, const u16* __restrict__ xc_bf,
    const float* __restrict__ xdb, const float* __restrict__ A_log,
    const unsigned* __restrict__ betak,
    float* __restrict__ hend, float* __restrict__ Ssum) {
  const int d = blockIdx.x * 256 + threadIdx.x;
  const int c = blockIdx.y;
  const int b = blockIdx.z;
  __shared__ float Bsh[SCH][16];
  const float beta = fmaxf(0.0f, -funkey(betak[0]));
  const int t0 = b * LL + c * SCH;
  for (int i = threadIdx.x; i < SCH * 16; i += 256) {
    int tt = i >> 4, n = i & 15;
    Bsh[tt][n] = xdb[(size_t)(t0 + tt) * 96 + 64 + n] + beta;
  }
  __syncthreads();
  float Av2[16];
#pragma unroll
  for (int n = 0; n < 16; ++n) Av2[n] = expf(A_log[d * 16 + n]) * LOG2E;
  float h[16];
#pragma unroll
  for (int n = 0; n < 16; ++n) h[n] = 0.f;
  float S = 0.f;
  for (int tt = 0; tt < SCH; ++tt) {
    int t = t0 + tt;
    float dv = bf2f(delta[(size_t)t * DI + d]);
    float xv = bf2f(xc_bf[(size_t)t * DI + d]);
    float dx = dv * xv;
    S += dv;
#pragma unroll
    for (int n = 0; n < 16; ++n) {
      float a = __builtin_amdgcn_exp2f(-dv * Av2[n]);
      h[n] = a * h[n] + dx * Bsh[tt][n];
    }
  }
  size_t base = (((size_t)(b * NCH + c) * DI) + d) * 16;
#pragma unroll
  for (int n = 0; n < 16; ++n) hend[base + n] = h[n];
  Ssum[((size_t)(b * NCH + c) * DI) + d] = S;
}

// ---------------------------------------------------------------------------
// scan pass3': inline prefix over predecessor chunks' local hend (replaces
// the old pass2 dispatch), then rescan chunk + gate + D -> ybf.
// ---------------------------------------------------------------------------
__global__ __launch_bounds__(256) void scan_pass3p(
    const u16* __restrict__ delta, const u16* __restrict__ xc_bf,
    const float* __restrict__ xdb, const u16* __restrict__ xz_bf,
    const float* __restrict__ A_log, const float* __restrict__ Dp,
    const unsigned* __restrict__ betak, const float* __restrict__ hloc,
    const float* __restrict__ Ssum, u16* __restrict__ ybf) {
  const int d = blockIdx.x * 256 + threadIdx.x;
  const int c = blockIdx.y;
  const int b = blockIdx.z;
  __shared__ float Bsh[SCH][16];
  __shared__ float Csh[SCH][16];
  const float beta = fmaxf(0.0f, -funkey(betak[0]));
  const int t0 = b * LL + c * SCH;
  for (int i = threadIdx.x; i < SCH * 16; i += 256) {
    int tt = i >> 4, n = i & 15;
    size_t row = (size_t)(t0 + tt) * 96;
    Bsh[tt][n] = xdb[row + 64 + n] + beta;
    Csh[tt][n] = xdb[row + 80 + n];
  }
  __syncthreads();
  float Av2[16];
#pragma unroll
  for (int n = 0; n < 16; ++n) Av2[n] = expf(A_log[d * 16 + n]) * LOG2E;
  float h[16];
#pragma unroll
  for (int n = 0; n < 16; ++n) h[n] = 0.f;
  // inline prefix: h-start = scan over predecessor chunks' local aggregates
  for (int j = 0; j < c; ++j) {
    size_t cb = ((size_t)(b * NCH + j) * DI) + d;
    float S = Ssum[cb];
    const float4* hl = (const float4*)&hloc[cb * 16];
    float hv[16];
    *(float4*)&hv[0]  = hl[0];
    *(float4*)&hv[4]  = hl[1];
    *(float4*)&hv[8]  = hl[2];
    *(float4*)&hv[12] = hl[3];
#pragma unroll
    for (int n = 0; n < 16; ++n) {
      float pr = __builtin_amdgcn_exp2f(-Av2[n] * S);
      h[n] = pr * h[n] + hv[n];
    }
  }
  const float Dd = Dp[d];
  for (int tt = 0; tt < SCH; ++tt) {
    int t = t0 + tt;
    float dv = bf2f(delta[(size_t)t * DI + d]);
    float xv = bf2f(xc_bf[(size_t)t * DI + d]);
    float dx = dv * xv;
    float yv = 0.f;
#pragma unroll
    for (int n = 0; n < 16; ++n) {
      float a = __builtin_amdgcn_exp2f(-dv * Av2[n]);
      h[n] = a * h[n] + dx * Bsh[tt][n];
      yv += h[n] * Csh[tt][n];
    }
    float zv = bf2f(xz_bf[(size_t)t * (2 * DI) + DI + d]);
    float outv = (yv + xv * Dd) * (zv / (1.0f + expf(-zv)));
    ybf[(size_t)t * DI + d] = f2bf(outv);
  }
}

extern "C" void kernel_launch(void* const* d_in, const int* in_sizes, int n_in,
                              void* d_out, int out_size, void* d_ws, size_t ws_size,
                              hipStream_t stream) {
  const float* hs      = (const float*)d_in[0];
  const float* W_in    = (const float*)d_in[1];
  const float* conv_w  = (const float*)d_in[2];
  const float* conv_b  = (const float*)d_in[3];
  const float* W_x     = (const float*)d_in[4];
  const float* W_dt    = (const float*)d_in[5];
  const float* dt_bias = (const float*)d_in[6];
  const float* W_out   = (const float*)d_in[7];
  const float* A_log   = (const float*)d_in[8];
  const float* Dp      = (const float*)d_in[9];
  float* out = (float*)d_out;

  float* ws       = (float*)d_ws;
  float* xz_bfR   = ws;                                  // 4,194,304 f
  float* xcv_bfR  = xz_bfR + (size_t)TT * 2 * DI / 2;    // 2,097,152 f
  float* xdb      = xcv_bfR + (size_t)TT * DI / 2;       //   196,608 f
  float* dlt_bfR  = xdb + (size_t)TT * 96;               // 2,097,152 f
  float* betab    = dlt_bfR + (size_t)TT * DI / 2;       //        64 f
  float* hend     = betab + 64;                          // 2,097,152 f
  float* Ssum     = hend + (size_t)NB * NCH * DI * 16;   //   131,072 f
  float* hs_bfR   = Ssum + (size_t)NB * NCH * DI;        // 1,048,576 f
  float* win_bfR  = hs_bfR + (size_t)TT * DM / 2;        // 2,097,152 f

  u16* xz_bf   = (u16*)xz_bfR;
  u16* xcv_bf  = (u16*)xcv_bfR;
  u16* dlt_bf  = (u16*)dlt_bfR;
  u16* hs_bf   = (u16*)hs_bfR;
  u16* win_bf  = (u16*)win_bfR;
  unsigned* betakey = (unsigned*)betab;
  u16* ybf     = (u16*)win_bfR;   // aliases win_bf (dead after GEMM1)

  dim3 blk(256);

  // 1) cast hs+W_in to bf16; zero xdb/out; init betakey
  cast2<<<8384, blk, 0, stream>>>(hs, W_in, hs_bf, win_bf, xdb, out, betakey);

  // 2) xz = hs @ W_in^T  (2048x4096x1024) bf16 gload path -> bf16 xz
  gemm_k<128, 128, 0, 1, 0, 0, 0, 0, 0>
      <<<dim3(4096 / 128, TT / 128), blk, 0, stream>>>(
      hs_bf, win_bf, xz_bf, TT, 2 * DI, DM, DM, DM, DM, nullptr, nullptr, nullptr);

  // 3) conv + silu -> xcv_bf
  conv_silu4<<<(TT * DI / 4) / 256, blk, 0, stream>>>(xz_bf, conv_w, conv_b, xcv_bf);

  // 4) x_dbl: (2048x128x2048) A=xcv bf16, B=W_x fp32 reg-staged (96 real rows),
  //    split-K=16 (512 blocks), atomicAdd into fp32 xdb cols<96
  gemm_k<64, 128, 0, 2, 96, 0, 1, 96, 0>
      <<<dim3(1, TT / 64, 16), blk, 0, stream>>>(
      xcv_bf, W_x, xdb, TT, 128, DI, DI, DI, DI / 16, nullptr, nullptr, nullptr);

  // 5) delta: A=xdb cols0..63 fp32 (lda=96), B=W_dt fp32, softplus/clip -> bf16;
  //    blocks 0..63 also reduce beta-min from xdb into betakey
  gemm_k<64, 128, 1, 1, 0, 1, 1, 0, 1>
      <<<dim3(DI / 128, TT / 64), blk, 0, stream>>>(
      xdb, W_dt, dlt_bf, TT, DI, DTR, 96, DTR, DTR, dt_bias, xdb, betakey);

  // 6) scan pass1: local chunk scans
  scan_pass1<<<dim3(DI / 256, NCH, NB), blk, 0, stream>>>(
      dlt_bf, xcv_bf, xdb, A_log, betakey, hend, Ssum);

  // 7) scan pass3': inline prefix + rescan + gate -> ybf
  scan_pass3p<<<dim3(DI / 256, NCH, NB), blk, 0, stream>>>(
      dlt_bf, xcv_bf, xdb, xz_bf, A_log, Dp, betakey, hend, Ssum, ybf);

  // 8) out = y @ W_out^T (2048x1024x2048), B=W_out fp32 reg-staged,
  //    split-K=4, atomicAdd into zeroed out
  gemm_k<128, 128, 0, 2, 0, 0, 1, 0, 0>
      <<<dim3(DM / 128, TT / 128, 4), blk, 0, stream>>>(
      ybf, W_out, out, TT, DM, DI, DI, DI, DI / 4, nullptr, nullptr, nullptr);
}

// Round 7
// 263.380 us; speedup vs baseline: 4.6941x; 1.1891x over previous
//
#include <hip/hip_runtime.h>
#include <math.h>

// Dims fixed by setup_inputs: d_model=1024, d_inner=2048, d_state=16,
// d_conv=4, dt_rank=64, B=2, L=1024. Tokens T = 2048.
#define DM 1024
#define DI 2048
#define DS 16
#define DTR 64
#define NB 2
#define LL 1024
#define TT (NB*LL)
#define SCH 32            // scan chunk length -> 512 blocks -> 2/CU
#define NCH (LL/SCH)      // 32 chunks per sequence

typedef unsigned short u16;
typedef __attribute__((ext_vector_type(8))) short bf16x8;
typedef __attribute__((ext_vector_type(4))) float f32x4;

#define LOG2E 1.4426950408889634f

__device__ inline u16 f2bf(float f) {   // RNE f32->bf16
  union { float f; unsigned u; } c; c.f = f;
  unsigned u = c.u;
  return (u16)((u + 0x7fffu + ((u >> 16) & 1u)) >> 16);
}
__device__ inline float bf2f(u16 u) {
  union { unsigned u; float f; } c; c.u = ((unsigned)u) << 16;
  return c.f;
}

// order-preserving f32 <-> u32 key (for atomicMin-based global min)
__device__ inline unsigned fkey(float f) {
  union { float f; unsigned u; } c; c.f = f;
  return (c.u & 0x80000000u) ? ~c.u : (c.u | 0x80000000u);
}
__device__ inline float funkey(unsigned k) {
  union { unsigned u; float f; } c;
  c.u = (k & 0x80000000u) ? (k & 0x7fffffffu) : ~k;
  return c.f;
}

__device__ inline bf16x8 cvt8(float4 a, float4 b) {
  bf16x8 w;
  w[0] = (short)f2bf(a.x); w[1] = (short)f2bf(a.y);
  w[2] = (short)f2bf(a.z); w[3] = (short)f2bf(a.w);
  w[4] = (short)f2bf(b.x); w[5] = (short)f2bf(b.y);
  w[6] = (short)f2bf(b.z); w[7] = (short)f2bf(b.w);
  return w;
}

#define GLDS16(g, l) __builtin_amdgcn_global_load_lds( \
    (const __attribute__((address_space(1))) unsigned int*)(g), \
    (__attribute__((address_space(3))) unsigned int*)(l), 16, 0, 0)

// ---------------------------------------------------------------------------
// bf16 MFMA GEMM: C[M,N] = A[M,K] @ B[N,K]^T.
// ASRC: 0 = bf16 A via global_load_lds; 1 = fp32 A, reg-staged (float4 x2 ->
//       RNE cvt -> LDS, same layout). B is ALWAYS bf16 via global_load_lds
//       (round-6 lesson: fp32 reg-staged B = -26us+ on the big GEMM).
// EPI=1: clip(softplus(v+bias[col]),1e-4,20).
// OB=1: bf16 store. OB=2: fp32 atomicAdd; if CGd>0 only cols<CGd, ldc=CGd.
// BMIN=1: flat blocks 0..63 first reduce min over minsrc[t*96+64..79] into
//         betakey (order-preserving key, atomicMin).
// ---------------------------------------------------------------------------
template<int BM, int BN, int EPI, int OB, int CGd, int ASRC, int BMIN>
__global__ __launch_bounds__(256) void gemm_k(
    const void* __restrict__ Av, const u16* __restrict__ B,
    void* __restrict__ Cv, int M, int N, int K, int lda, int ldb, int kpb,
    const float* __restrict__ bias,
    const float* __restrict__ minsrc, unsigned* __restrict__ betakey) {
  constexpr int WAVES_M = BM / 64;
  constexpr int WAVES_N = 4 / WAVES_M;
  constexpr int WTM = 4;
  constexpr int WTN = BN / (WAVES_N * 16);
  constexpr int ASLABS = BM / 16;
  constexpr int SLABS = (BM + BN) / 16;
  constexpr int SPW = SLABS / 4;
  __shared__ u16 As[BM * 32];
  __shared__ u16 Bs[BN * 32];
  __shared__ float sm4[4];
  const int tid = threadIdx.x;
  const int wave = tid >> 6;
  const int lane = tid & 63;
  const int bm = blockIdx.y * BM;
  const int bn = blockIdx.x * BN;
  const int wm = (wave / WAVES_N) * 64;
  const int wn = (wave % WAVES_N) * (WTN * 16);
  const int r4 = lane >> 2;
  const int kc = (lane & 3) * 8;
  const int fr = lane & 15;
  const int fq = lane >> 4;
  const int koff = blockIdx.z * kpb;
  float* C = (float*)Cv;
  u16* C16 = (u16*)Cv;

  if constexpr (BMIN == 1) {   // beta-min prologue (flat blocks 0..63)
    int fb = blockIdx.y * gridDim.x + blockIdx.x;
    if (fb < 64) {
      const int t0 = fb * 32;
      float mn = 3.4e38f;
      for (int i = tid; i < 32 * 16; i += 256) {
        int t = t0 + (i >> 4), n = i & 15;
        mn = fminf(mn, minsrc[t * 96 + 64 + n]);
      }
#pragma unroll
      for (int o = 32; o; o >>= 1) mn = fminf(mn, __shfl_down(mn, o));
      if ((tid & 63) == 0) sm4[tid >> 6] = mn;
      __syncthreads();
      if (tid == 0)
        atomicMin(betakey, fkey(fminf(fminf(sm4[0], sm4[1]), fminf(sm4[2], sm4[3]))));
      __syncthreads();
    }
  }

  f32x4 acc[WTM][WTN];
#pragma unroll
  for (int i = 0; i < WTM; ++i)
#pragma unroll
    for (int j = 0; j < WTN; ++j) acc[i][j] = (f32x4){0.f, 0.f, 0.f, 0.f};

  for (int k0 = koff; k0 < koff + kpb; k0 += 32) {
#pragma unroll
    for (int s = wave * SPW; s < (wave + 1) * SPW; ++s) {
      if (s < ASLABS) {
        int row = s * 16 + r4;
        if constexpr (ASRC == 0) {
          GLDS16((const u16*)Av + (size_t)(bm + row) * lda + k0 + kc, &As[s * 512]);
        } else {
          const float* src = (const float*)Av + (size_t)(bm + row) * lda + k0 + kc;
          float4 v0 = *(const float4*)src;
          float4 v1 = *(const float4*)(src + 4);
          *(bf16x8*)&As[s * 512 + lane * 8] = cvt8(v0, v1);
        }
      } else {
        int bs = s - ASLABS;
        int row = bs * 16 + r4;
        GLDS16(B + (size_t)(bn + row) * ldb + k0 + kc, &Bs[bs * 512]);
      }
    }
    __syncthreads();
    bf16x8 af[WTM], bf[WTN];
#pragma unroll
    for (int i = 0; i < WTM; ++i)
      af[i] = *(const bf16x8*)&As[(wm + 16 * i + fr) * 32 + fq * 8];
#pragma unroll
    for (int j = 0; j < WTN; ++j)
      bf[j] = *(const bf16x8*)&Bs[(wn + 16 * j + fr) * 32 + fq * 8];
#pragma unroll
    for (int i = 0; i < WTM; ++i)
#pragma unroll
      for (int j = 0; j < WTN; ++j)
        acc[i][j] = __builtin_amdgcn_mfma_f32_16x16x32_bf16(af[i], bf[j], acc[i][j], 0, 0, 0);
    __syncthreads();
  }

#pragma unroll
  for (int i = 0; i < WTM; ++i) {
    int row0 = bm + wm + 16 * i + fq * 4;
#pragma unroll
    for (int j = 0; j < WTN; ++j) {
      int col = bn + wn + 16 * j + fr;
#pragma unroll
      for (int r = 0; r < 4; ++r) {
        float v = acc[i][j][r];
        if (EPI == 1) {
          v += bias[col];
          float sp = (v > 20.0f) ? v : log1pf(expf(v));
          v = fminf(fmaxf(sp, 1e-4f), 20.0f);
        }
        if (OB == 1) {
          C16[(size_t)(row0 + r) * N + col] = f2bf(v);
        } else {  // OB == 2
          if (CGd == 0 || col < CGd) {
            const int ldc = (CGd > 0) ? CGd : N;
            atomicAdd(&C[(size_t)(row0 + r) * ldc + col], v);
          }
        }
      }
    }
  }
}

// ---------------------------------------------------------------------------
// Fused bf16 casts + zero-inits: hs, W_in, W_out, W_x (pad to 128 rows),
// W_dt; zero xdb (atomic target) and out (atomic target); init betakey.
// ---------------------------------------------------------------------------
__global__ __launch_bounds__(256) void cast_all(
    const float* __restrict__ hs, const float* __restrict__ win,
    const float* __restrict__ wout, const float* __restrict__ wx,
    const float* __restrict__ wdt,
    u16* __restrict__ hs_bf, u16* __restrict__ win_bf,
    u16* __restrict__ wout_bf, u16* __restrict__ wx_bf,
    u16* __restrict__ wdt_bf, float* __restrict__ xdb,
    float* __restrict__ outz, unsigned* __restrict__ betakey) {
  int gid = blockIdx.x * 256 + threadIdx.x;  // 2,768,896 total
  if (gid == 0) betakey[0] = 0xFFFFFFFFu;
  const float* src; u16* dst; int off;
  if (gid < 524288)       { src = hs;   dst = hs_bf;   off = gid; }
  else if (gid < 1572864) { src = win;  dst = win_bf;  off = gid - 524288; }
  else if (gid < 2097152) { src = wout; dst = wout_bf; off = gid - 1572864; }
  else if (gid < 2146304) { src = wx;   dst = wx_bf;   off = gid - 2097152; }
  else if (gid < 2179072) { src = wdt;  dst = wdt_bf;  off = gid - 2146304; }
  else if (gid < 2195456) {  // zero-fill wx_bf rows 96..127
    ushort4 z4 = {0, 0, 0, 0};
    ((ushort4*)wx_bf)[49152 + gid - 2179072] = z4;
    return;
  } else if (gid < 2244608) {  // zero xdb (196,608 f)
    float4 z = {0.f, 0.f, 0.f, 0.f};
    ((float4*)xdb)[gid - 2195456] = z;
    return;
  } else {                     // zero out (2,097,152 f)
    float4 z = {0.f, 0.f, 0.f, 0.f};
    ((float4*)outz)[gid - 2244608] = z;
    return;
  }
  float4 v = ((const float4*)src)[off];
  ushort4 o;
  o.x = f2bf(v.x); o.y = f2bf(v.y); o.z = f2bf(v.z); o.w = f2bf(v.w);
  ((ushort4*)dst)[off] = o;
}

// ---------------------------------------------------------------------------
// Causal depthwise conv (k=4, pad 3) + bias + SiLU. bf16 in, bf16 out.
// ---------------------------------------------------------------------------
__global__ __launch_bounds__(256) void conv_silu4(
    const u16* __restrict__ xz, const float* __restrict__ w,
    const float* __restrict__ cb, u16* __restrict__ xc_bf) {
  int gid = blockIdx.x * 256 + threadIdx.x;  // TT*512
  int dq = (gid & 511) * 4;
  int t = gid >> 9;
  int l = t & (LL - 1);
  float wv[4][4];
#pragma unroll
  for (int j = 0; j < 4; ++j) {
    float4 ww = *(const float4*)&w[(dq + j) * 4];
    wv[j][0] = ww.x; wv[j][1] = ww.y; wv[j][2] = ww.z; wv[j][3] = ww.w;
  }
  float4 acc = *(const float4*)&cb[dq];
#pragma unroll
  for (int k = 0; k < 4; ++k) {
    int ll = l - 3 + k;
    if (ll < 0) continue;
    ushort4 xv = *(const ushort4*)&xz[(size_t)(t - 3 + k) * (2 * DI) + dq];
    acc.x += bf2f(xv.x) * wv[0][k]; acc.y += bf2f(xv.y) * wv[1][k];
    acc.z += bf2f(xv.z) * wv[2][k]; acc.w += bf2f(xv.w) * wv[3][k];
  }
  acc.x /= (1.0f + expf(-acc.x)); acc.y /= (1.0f + expf(-acc.y));
  acc.z /= (1.0f + expf(-acc.z)); acc.w /= (1.0f + expf(-acc.w));
  ushort4 o;
  o.x = f2bf(acc.x); o.y = f2bf(acc.y); o.z = f2bf(acc.z); o.w = f2bf(acc.w);
  *(ushort4*)&xc_bf[(size_t)t * DI + dq] = o;
}

// ---------------------------------------------------------------------------
// Chunked selective scan, SCH=32 (512 blocks/pass -> 2/CU). 3 kernels.
// ---------------------------------------------------------------------------
__global__ __launch_bounds__(256) void scan_pass1(
    const u16* __restrict__ delta, const u16* __restrict__ xc_bf,
    const float* __restrict__ xdb, const float* __restrict__ A_log,
    const unsigned* __restrict__ betak,
    float* __restrict__ hend, float* __restrict__ Ssum) {
  const int d = blockIdx.x * 256 + threadIdx.x;
  const int c = blockIdx.y;
  const int b = blockIdx.z;
  __shared__ float Bsh[SCH][16];
  const float beta = fmaxf(0.0f, -funkey(betak[0]));
  const int t0 = b * LL + c * SCH;
  for (int i = threadIdx.x; i < SCH * 16; i += 256) {
    int tt = i >> 4, n = i & 15;
    Bsh[tt][n] = xdb[(size_t)(t0 + tt) * 96 + 64 + n] + beta;
  }
  __syncthreads();
  float Av2[16];
#pragma unroll
  for (int n = 0; n < 16; ++n) Av2[n] = expf(A_log[d * 16 + n]) * LOG2E;
  float h[16];
#pragma unroll
  for (int n = 0; n < 16; ++n) h[n] = 0.f;
  float S = 0.f;
  for (int tt = 0; tt < SCH; ++tt) {
    int t = t0 + tt;
    float dv = bf2f(delta[(size_t)t * DI + d]);
    float xv = bf2f(xc_bf[(size_t)t * DI + d]);
    float dx = dv * xv;
    S += dv;
#pragma unroll
    for (int n = 0; n < 16; ++n) {
      float a = __builtin_amdgcn_exp2f(-dv * Av2[n]);
      h[n] = a * h[n] + dx * Bsh[tt][n];
    }
  }
  size_t base = (((size_t)(b * NCH + c) * DI) + d) * 16;
#pragma unroll
  for (int n = 0; n < 16; ++n) hend[base + n] = h[n];
  Ssum[((size_t)(b * NCH + c) * DI) + d] = S;
}

__global__ __launch_bounds__(256) void scan_pass2(
    float* __restrict__ hend, const float* __restrict__ Ssum,
    const float* __restrict__ A_log) {
  int gid = blockIdx.x * 256 + threadIdx.x;   // 65536
  int n = gid & 15;
  int d = (gid >> 4) & (DI - 1);
  int b = gid >> 15;
  float Av2 = expf(A_log[d * 16 + n]) * LOG2E;
  float H = 0.f;
  for (int c = 0; c < NCH; ++c) {
    size_t cb = ((size_t)(b * NCH + c) * DI) + d;
    float hl = hend[cb * 16 + n];
    float p = __builtin_amdgcn_exp2f(-Av2 * Ssum[cb]);
    hend[cb * 16 + n] = H;
    H = p * H + hl;
  }
}

__global__ __launch_bounds__(256) void scan_pass3(
    const u16* __restrict__ delta, const u16* __restrict__ xc_bf,
    const float* __restrict__ xdb, const u16* __restrict__ xz_bf,
    const float* __restrict__ A_log, const float* __restrict__ Dp,
    const unsigned* __restrict__ betak, const float* __restrict__ hstart,
    u16* __restrict__ ybf) {
  const int d = blockIdx.x * 256 + threadIdx.x;
  const int c = blockIdx.y;
  const int b = blockIdx.z;
  __shared__ float Bsh[SCH][16];
  __shared__ float Csh[SCH][16];
  const float beta = fmaxf(0.0f, -funkey(betak[0]));
  const int t0 = b * LL + c * SCH;
  for (int i = threadIdx.x; i < SCH * 16; i += 256) {
    int tt = i >> 4, n = i & 15;
    size_t row = (size_t)(t0 + tt) * 96;
    Bsh[tt][n] = xdb[row + 64 + n] + beta;
    Csh[tt][n] = xdb[row + 80 + n];
  }
  __syncthreads();
  float Av2[16];
#pragma unroll
  for (int n = 0; n < 16; ++n) Av2[n] = expf(A_log[d * 16 + n]) * LOG2E;
  float h[16];
  size_t base = (((size_t)(b * NCH + c) * DI) + d) * 16;
#pragma unroll
  for (int n = 0; n < 16; ++n) h[n] = hstart[base + n];
  const float Dd = Dp[d];
  for (int tt = 0; tt < SCH; ++tt) {
    int t = t0 + tt;
    float dv = bf2f(delta[(size_t)t * DI + d]);
    float xv = bf2f(xc_bf[(size_t)t * DI + d]);
    float dx = dv * xv;
    float yv = 0.f;
#pragma unroll
    for (int n = 0; n < 16; ++n) {
      float a = __builtin_amdgcn_exp2f(-dv * Av2[n]);
      h[n] = a * h[n] + dx * Bsh[tt][n];
      yv += h[n] * Csh[tt][n];
    }
    float zv = bf2f(xz_bf[(size_t)t * (2 * DI) + DI + d]);
    float out = (yv + xv * Dd) * (zv / (1.0f + expf(-zv)));
    ybf[(size_t)t * DI + d] = f2bf(out);
  }
}

extern "C" void kernel_launch(void* const* d_in, const int* in_sizes, int n_in,
                              void* d_out, int out_size, void* d_ws, size_t ws_size,
                              hipStream_t stream) {
  const float* hs      = (const float*)d_in[0];
  const float* W_in    = (const float*)d_in[1];
  const float* conv_w  = (const float*)d_in[2];
  const float* conv_b  = (const float*)d_in[3];
  const float* W_x     = (const float*)d_in[4];
  const float* W_dt    = (const float*)d_in[5];
  const float* dt_bias = (const float*)d_in[6];
  const float* W_out   = (const float*)d_in[7];
  const float* A_log   = (const float*)d_in[8];
  const float* Dp      = (const float*)d_in[9];
  float* out = (float*)d_out;

  float* ws       = (float*)d_ws;
  float* xz_bfR   = ws;                                  // 4,194,304 f
  float* xcv_bfR  = xz_bfR + (size_t)TT * 2 * DI / 2;    // 2,097,152 f
  float* xdb      = xcv_bfR + (size_t)TT * DI / 2;       //   196,608 f
  float* dlt_bfR  = xdb + (size_t)TT * 96;               // 2,097,152 f
  float* betab    = dlt_bfR + (size_t)TT * DI / 2;       //        64 f
  float* hend     = betab + 64;                          // 2,097,152 f
  float* Ssum     = hend + (size_t)NB * NCH * DI * 16;   //   131,072 f
  float* hs_bfR   = Ssum + (size_t)NB * NCH * DI;        // 1,048,576 f
  float* win_bfR  = hs_bfR + (size_t)TT * DM / 2;        // 2,097,152 f
  float* wout_bfR = win_bfR + (size_t)2 * DI * DM / 2;   // 1,048,576 f
  float* wx_bfR   = wout_bfR + (size_t)DM * DI / 2;      //   131,072 f
  float* wdt_bfR  = wx_bfR + 131072;                     //    65,536 f

  u16* xz_bf   = (u16*)xz_bfR;
  u16* xcv_bf  = (u16*)xcv_bfR;
  u16* dlt_bf  = (u16*)dlt_bfR;
  u16* hs_bf   = (u16*)hs_bfR;
  u16* win_bf  = (u16*)win_bfR;
  u16* wout_bf = (u16*)wout_bfR;
  u16* wx_bf   = (u16*)wx_bfR;
  u16* wdt_bf  = (u16*)wdt_bfR;
  unsigned* betakey = (unsigned*)betab;
  u16* ybf     = (u16*)win_bfR;   // aliases win_bf (dead after GEMM1)

  dim3 blk(256);

  // 1) bf16 casts + zero xdb/out + betakey init
  cast_all<<<10816, blk, 0, stream>>>(hs, W_in, W_out, W_x, W_dt,
                                      hs_bf, win_bf, wout_bf, wx_bf, wdt_bf,
                                      xdb, out, betakey);

  // 2) xz = hs @ W_in^T  (2048x4096x1024) bf16 GLDS -> bf16 xz. 512 blocks.
  gemm_k<128, 128, 0, 1, 0, 0, 0>
      <<<dim3(4096 / 128, TT / 128), blk, 0, stream>>>(
      hs_bf, win_bf, xz_bf, TT, 2 * DI, DM, DM, DM, DM,
      nullptr, nullptr, nullptr);

  // 3) conv + silu -> xcv_bf
  conv_silu4<<<(TT * DI / 4) / 256, blk, 0, stream>>>(xz_bf, conv_w, conv_b, xcv_bf);

  // 4) x_dbl: (2048x128x2048) bf16 GLDS both, split-K=8, atomicAdd cols<96
  gemm_k<64, 128, 0, 2, 96, 0, 0>
      <<<dim3(1, TT / 64, 8), blk, 0, stream>>>(
      xcv_bf, wx_bf, xdb, TT, 128, DI, DI, DI, DI / 8,
      nullptr, nullptr, nullptr);

  // 5) delta: A = xdb cols0..63 fp32 reg-staged (lda=96), B = wdt_bf GLDS,
  //    softplus/clip -> bf16 dlt; blocks 0..63 also reduce beta-min (BMIN)
  gemm_k<64, 128, 1, 1, 0, 1, 1>
      <<<dim3(DI / 128, TT / 64), blk, 0, stream>>>(
      xdb, wdt_bf, dlt_bf, TT, DI, DTR, 96, DTR, DTR,
      dt_bias, xdb, betakey);

  // 6) chunked selective scan -> ybf
  scan_pass1<<<dim3(DI / 256, NCH, NB), blk, 0, stream>>>(
      dlt_bf, xcv_bf, xdb, A_log, betakey, hend, Ssum);
  scan_pass2<<<(NB * DI * DS) / 256, blk, 0, stream>>>(hend, Ssum, A_log);
  scan_pass3<<<dim3(DI / 256, NCH, NB), blk, 0, stream>>>(
      dlt_bf, xcv_bf, xdb, xz_bf, A_log, Dp, betakey, hend, ybf);

  // 7) out = y @ W_out^T (2048x1024x2048) bf16 GLDS both, split-K=4 atomic
  gemm_k<128, 128, 0, 2, 0, 0, 0>
      <<<dim3(DM / 128, TT / 128, 4), blk, 0, stream>>>(
      ybf, wout_bf, out, TT, DM, DI, DI, DI, DI / 4,
      nullptr, nullptr, nullptr);
}

// Round 8
// 239.007 us; speedup vs baseline: 5.1727x; 1.1020x over previous
//
#include <hip/hip_runtime.h>
#include <math.h>

// Dims fixed by setup_inputs: d_model=1024, d_inner=2048, d_state=16,
// d_conv=4, dt_rank=64, B=2, L=1024. Tokens T = 2048.
#define DM 1024
#define DI 2048
#define DS 16
#define DTR 64
#define NB 2
#define LL 1024
#define TT (NB*LL)
#define SCH 32            // scan chunk length -> 512 blocks -> 2/CU
#define NCH (LL/SCH)      // 32 chunks per sequence

typedef unsigned short u16;
typedef __attribute__((ext_vector_type(8))) short bf16x8;
typedef __attribute__((ext_vector_type(4))) float f32x4;

#define LOG2E 1.4426950408889634f
#define LN2   0.6931471805599453f

__device__ inline u16 f2bf(float f) {   // RNE f32->bf16
  union { float f; unsigned u; } c; c.f = f;
  unsigned u = c.u;
  return (u16)((u + 0x7fffu + ((u >> 16) & 1u)) >> 16);
}
__device__ inline float bf2f(u16 u) {
  union { unsigned u; float f; } c; c.u = ((unsigned)u) << 16;
  return c.f;
}

// fast SiLU: x * rcp(1 + exp2(-x*log2e)) -- HW v_exp/v_rcp, plenty for bf16
__device__ inline float fsilu(float x) {
  return x * __builtin_amdgcn_rcpf(1.0f + __builtin_amdgcn_exp2f(-x * LOG2E));
}

// order-preserving f32 <-> u32 key (for atomicMin-based global min)
__device__ inline unsigned fkey(float f) {
  union { float f; unsigned u; } c; c.f = f;
  return (c.u & 0x80000000u) ? ~c.u : (c.u | 0x80000000u);
}
__device__ inline float funkey(unsigned k) {
  union { unsigned u; float f; } c;
  c.u = (k & 0x80000000u) ? (k & 0x7fffffffu) : ~k;
  return c.f;
}

__device__ inline bf16x8 cvt8(float4 a, float4 b) {
  bf16x8 w;
  w[0] = (short)f2bf(a.x); w[1] = (short)f2bf(a.y);
  w[2] = (short)f2bf(a.z); w[3] = (short)f2bf(a.w);
  w[4] = (short)f2bf(b.x); w[5] = (short)f2bf(b.y);
  w[6] = (short)f2bf(b.z); w[7] = (short)f2bf(b.w);
  return w;
}

#define GLDS16(g, l) __builtin_amdgcn_global_load_lds( \
    (const __attribute__((address_space(1))) unsigned int*)(g), \
    (__attribute__((address_space(3))) unsigned int*)(l), 16, 0, 0)

// ---------------------------------------------------------------------------
// bf16 MFMA GEMM, 2-PHASE PIPELINED (T3-min): double-buffered LDS, next-tile
// STAGE issued before current-tile ds_read+MFMA, ONE vmcnt(0)+barrier per
// K-step (vs 2 barriers + zero-hiding drain in the old 1-phase loop).
// ASRC: 0 = bf16 A via global_load_lds; 1 = fp32 A reg-staged.
//       B is ALWAYS bf16 via global_load_lds (round-6 lesson).
// EPI=1: clip(softplus(v+bias[col]),1e-4,20).
// OB=1: bf16 store. OB=2: fp32 atomicAdd; if CGd>0 only cols<CGd, ldc=CGd.
// BMIN=1: flat blocks 0..63 first reduce min over minsrc[t*96+64..79] into
//         betakey (order-preserving key, atomicMin).
// ---------------------------------------------------------------------------
template<int BM, int BN, int EPI, int OB, int CGd, int ASRC, int BMIN>
__global__ __launch_bounds__(256) void gemm_k(
    const void* __restrict__ Av, const u16* __restrict__ B,
    void* __restrict__ Cv, int M, int N, int K, int lda, int ldb, int kpb,
    const float* __restrict__ bias,
    const float* __restrict__ minsrc, unsigned* __restrict__ betakey) {
  constexpr int WAVES_M = BM / 64;
  constexpr int WAVES_N = 4 / WAVES_M;
  constexpr int WTM = 4;
  constexpr int WTN = BN / (WAVES_N * 16);
  constexpr int ASLABS = BM / 16;
  constexpr int SLABS = (BM + BN) / 16;
  constexpr int SPW = SLABS / 4;
  __shared__ u16 As[2][BM * 32];
  __shared__ u16 Bs[2][BN * 32];
  __shared__ float sm4[4];
  const int tid = threadIdx.x;
  const int wave = tid >> 6;
  const int lane = tid & 63;
  const int bm = blockIdx.y * BM;
  const int bn = blockIdx.x * BN;
  const int wm = (wave / WAVES_N) * 64;
  const int wn = (wave % WAVES_N) * (WTN * 16);
  const int r4 = lane >> 2;
  const int kc = (lane & 3) * 8;
  const int fr = lane & 15;
  const int fq = lane >> 4;
  const int koff = blockIdx.z * kpb;
  float* C = (float*)Cv;
  u16* C16 = (u16*)Cv;

  if constexpr (BMIN == 1) {   // beta-min prologue (flat blocks 0..63)
    int fb = blockIdx.y * gridDim.x + blockIdx.x;
    if (fb < 64) {
      const int t0 = fb * 32;
      float mn = 3.4e38f;
      for (int i = tid; i < 32 * 16; i += 256) {
        int t = t0 + (i >> 4), n = i & 15;
        mn = fminf(mn, minsrc[t * 96 + 64 + n]);
      }
#pragma unroll
      for (int o = 32; o; o >>= 1) mn = fminf(mn, __shfl_down(mn, o));
      if ((tid & 63) == 0) sm4[tid >> 6] = mn;
      __syncthreads();
      if (tid == 0)
        atomicMin(betakey, fkey(fminf(fminf(sm4[0], sm4[1]), fminf(sm4[2], sm4[3]))));
      __syncthreads();
    }
  }

  auto stage = [&](int k0, int bufi) {
#pragma unroll
    for (int s = wave * SPW; s < (wave + 1) * SPW; ++s) {
      if (s < ASLABS) {
        int row = s * 16 + r4;
        if constexpr (ASRC == 0) {
          GLDS16((const u16*)Av + (size_t)(bm + row) * lda + k0 + kc,
                 &As[bufi][s * 512]);
        } else {
          const float* src = (const float*)Av + (size_t)(bm + row) * lda + k0 + kc;
          float4 v0 = *(const float4*)src;
          float4 v1 = *(const float4*)(src + 4);
          *(bf16x8*)&As[bufi][s * 512 + lane * 8] = cvt8(v0, v1);
        }
      } else {
        int bs = s - ASLABS;
        int row = bs * 16 + r4;
        GLDS16(B + (size_t)(bn + row) * ldb + k0 + kc, &Bs[bufi][bs * 512]);
      }
    }
  };

  f32x4 acc[WTM][WTN];
#pragma unroll
  for (int i = 0; i < WTM; ++i)
#pragma unroll
    for (int j = 0; j < WTN; ++j) acc[i][j] = (f32x4){0.f, 0.f, 0.f, 0.f};

  const int NT = kpb >> 5;
  stage(koff, 0);
  asm volatile("s_waitcnt vmcnt(0) lgkmcnt(0)" ::: "memory");
  __builtin_amdgcn_s_barrier();
  for (int t = 0; t < NT; ++t) {
    const int cur = t & 1;
    if (t + 1 < NT) stage(koff + (t + 1) * 32, cur ^ 1);   // async, in flight
    bf16x8 af[WTM], bf[WTN];
#pragma unroll
    for (int i = 0; i < WTM; ++i)
      af[i] = *(const bf16x8*)&As[cur][(wm + 16 * i + fr) * 32 + fq * 8];
#pragma unroll
    for (int j = 0; j < WTN; ++j)
      bf[j] = *(const bf16x8*)&Bs[cur][(wn + 16 * j + fr) * 32 + fq * 8];
#pragma unroll
    for (int i = 0; i < WTM; ++i)
#pragma unroll
      for (int j = 0; j < WTN; ++j)
        acc[i][j] = __builtin_amdgcn_mfma_f32_16x16x32_bf16(af[i], bf[j], acc[i][j], 0, 0, 0);
    if (t + 1 < NT) {   // drain next-tile stage (hidden under the MFMA above)
      asm volatile("s_waitcnt vmcnt(0) lgkmcnt(0)" ::: "memory");
      __builtin_amdgcn_s_barrier();
    }
  }

#pragma unroll
  for (int i = 0; i < WTM; ++i) {
    int row0 = bm + wm + 16 * i + fq * 4;
#pragma unroll
    for (int j = 0; j < WTN; ++j) {
      int col = bn + wn + 16 * j + fr;
#pragma unroll
      for (int r = 0; r < 4; ++r) {
        float v = acc[i][j][r];
        if (EPI == 1) {
          v += bias[col];
          float sp;
          if (v > 20.0f) sp = v;
          else sp = __builtin_amdgcn_logf(1.0f + __builtin_amdgcn_exp2f(v * LOG2E)) * LN2;
          v = fminf(fmaxf(sp, 1e-4f), 20.0f);
        }
        if (OB == 1) {
          C16[(size_t)(row0 + r) * N + col] = f2bf(v);
        } else {  // OB == 2
          if (CGd == 0 || col < CGd) {
            const int ldc = (CGd > 0) ? CGd : N;
            atomicAdd(&C[(size_t)(row0 + r) * ldc + col], v);
          }
        }
      }
    }
  }
}

// ---------------------------------------------------------------------------
// Fused bf16 casts + zero-inits: hs, W_in, W_out, W_x (pad to 128 rows),
// W_dt; zero xdb (atomic target) and out (atomic target); init betakey.
// ---------------------------------------------------------------------------
__global__ __launch_bounds__(256) void cast_all(
    const float* __restrict__ hs, const float* __restrict__ win,
    const float* __restrict__ wout, const float* __restrict__ wx,
    const float* __restrict__ wdt,
    u16* __restrict__ hs_bf, u16* __restrict__ win_bf,
    u16* __restrict__ wout_bf, u16* __restrict__ wx_bf,
    u16* __restrict__ wdt_bf, float* __restrict__ xdb,
    float* __restrict__ outz, unsigned* __restrict__ betakey) {
  int gid = blockIdx.x * 256 + threadIdx.x;  // 2,768,896 total
  if (gid == 0) betakey[0] = 0xFFFFFFFFu;
  const float* src; u16* dst; int off;
  if (gid < 524288)       { src = hs;   dst = hs_bf;   off = gid; }
  else if (gid < 1572864) { src = win;  dst = win_bf;  off = gid - 524288; }
  else if (gid < 2097152) { src = wout; dst = wout_bf; off = gid - 1572864; }
  else if (gid < 2146304) { src = wx;   dst = wx_bf;   off = gid - 2097152; }
  else if (gid < 2179072) { src = wdt;  dst = wdt_bf;  off = gid - 2146304; }
  else if (gid < 2195456) {  // zero-fill wx_bf rows 96..127
    ushort4 z4 = {0, 0, 0, 0};
    ((ushort4*)wx_bf)[49152 + gid - 2179072] = z4;
    return;
  } else if (gid < 2244608) {  // zero xdb (196,608 f)
    float4 z = {0.f, 0.f, 0.f, 0.f};
    ((float4*)xdb)[gid - 2195456] = z;
    return;
  } else {                     // zero out (2,097,152 f)
    float4 z = {0.f, 0.f, 0.f, 0.f};
    ((float4*)outz)[gid - 2244608] = z;
    return;
  }
  float4 v = ((const float4*)src)[off];
  ushort4 o;
  o.x = f2bf(v.x); o.y = f2bf(v.y); o.z = f2bf(v.z); o.w = f2bf(v.w);
  ((ushort4*)dst)[off] = o;
}

// ---------------------------------------------------------------------------
// Causal depthwise conv (k=4, pad 3) + bias + SiLU. bf16 in, bf16 out.
// ---------------------------------------------------------------------------
__global__ __launch_bounds__(256) void conv_silu4(
    const u16* __restrict__ xz, const float* __restrict__ w,
    const float* __restrict__ cb, u16* __restrict__ xc_bf) {
  int gid = blockIdx.x * 256 + threadIdx.x;  // TT*512
  int dq = (gid & 511) * 4;
  int t = gid >> 9;
  int l = t & (LL - 1);
  float wv[4][4];
#pragma unroll
  for (int j = 0; j < 4; ++j) {
    float4 ww = *(const float4*)&w[(dq + j) * 4];
    wv[j][0] = ww.x; wv[j][1] = ww.y; wv[j][2] = ww.z; wv[j][3] = ww.w;
  }
  float4 acc = *(const float4*)&cb[dq];
#pragma unroll
  for (int k = 0; k < 4; ++k) {
    int ll = l - 3 + k;
    if (ll < 0) continue;
    ushort4 xv = *(const ushort4*)&xz[(size_t)(t - 3 + k) * (2 * DI) + dq];
    acc.x += bf2f(xv.x) * wv[0][k]; acc.y += bf2f(xv.y) * wv[1][k];
    acc.z += bf2f(xv.z) * wv[2][k]; acc.w += bf2f(xv.w) * wv[3][k];
  }
  acc.x = fsilu(acc.x); acc.y = fsilu(acc.y);
  acc.z = fsilu(acc.z); acc.w = fsilu(acc.w);
  ushort4 o;
  o.x = f2bf(acc.x); o.y = f2bf(acc.y); o.z = f2bf(acc.z); o.w = f2bf(acc.w);
  *(ushort4*)&xc_bf[(size_t)t * DI + dq] = o;
}

// ---------------------------------------------------------------------------
// Chunked selective scan, SCH=32 (512 blocks/pass -> 2/CU). 3 kernels.
// ---------------------------------------------------------------------------
__global__ __launch_bounds__(256) void scan_pass1(
    const u16* __restrict__ delta, const u16* __restrict__ xc_bf,
    const float* __restrict__ xdb, const float* __restrict__ A_log,
    const unsigned* __restrict__ betak,
    float* __restrict__ hend, float* __restrict__ Ssum) {
  const int d = blockIdx.x * 256 + threadIdx.x;
  const int c = blockIdx.y;
  const int b = blockIdx.z;
  __shared__ float Bsh[SCH][16];
  const float beta = fmaxf(0.0f, -funkey(betak[0]));
  const int t0 = b * LL + c * SCH;
  for (int i = threadIdx.x; i < SCH * 16; i += 256) {
    int tt = i >> 4, n = i & 15;
    Bsh[tt][n] = xdb[(size_t)(t0 + tt) * 96 + 64 + n] + beta;
  }
  __syncthreads();
  float Av2[16];
#pragma unroll
  for (int n = 0; n < 16; ++n)
    Av2[n] = __builtin_amdgcn_exp2f(A_log[d * 16 + n] * LOG2E) * LOG2E;
  float h[16];
#pragma unroll
  for (int n = 0; n < 16; ++n) h[n] = 0.f;
  float S = 0.f;
  for (int tt = 0; tt < SCH; ++tt) {
    int t = t0 + tt;
    float dv = bf2f(delta[(size_t)t * DI + d]);
    float xv = bf2f(xc_bf[(size_t)t * DI + d]);
    float dx = dv * xv;
    S += dv;
#pragma unroll
    for (int n = 0; n < 16; ++n) {
      float a = __builtin_amdgcn_exp2f(-dv * Av2[n]);
      h[n] = a * h[n] + dx * Bsh[tt][n];
    }
  }
  size_t base = (((size_t)(b * NCH + c) * DI) + d) * 16;
#pragma unroll
  for (int n = 0; n < 16; ++n) hend[base + n] = h[n];
  Ssum[((size_t)(b * NCH + c) * DI) + d] = S;
}

__global__ __launch_bounds__(256) void scan_pass2(
    float* __restrict__ hend, const float* __restrict__ Ssum,
    const float* __restrict__ A_log) {
  int gid = blockIdx.x * 256 + threadIdx.x;   // 65536
  int n = gid & 15;
  int d = (gid >> 4) & (DI - 1);
  int b = gid >> 15;
  float Av2 = __builtin_amdgcn_exp2f(A_log[d * 16 + n] * LOG2E) * LOG2E;
  float H = 0.f;
  for (int c = 0; c < NCH; ++c) {
    size_t cb = ((size_t)(b * NCH + c) * DI) + d;
    float hl = hend[cb * 16 + n];
    float p = __builtin_amdgcn_exp2f(-Av2 * Ssum[cb]);
    hend[cb * 16 + n] = H;
    H = p * H + hl;
  }
}

__global__ __launch_bounds__(256) void scan_pass3(
    const u16* __restrict__ delta, const u16* __restrict__ xc_bf,
    const float* __restrict__ xdb, const u16* __restrict__ xz_bf,
    const float* __restrict__ A_log, const float* __restrict__ Dp,
    const unsigned* __restrict__ betak, const float* __restrict__ hstart,
    u16* __restrict__ ybf) {
  const int d = blockIdx.x * 256 + threadIdx.x;
  const int c = blockIdx.y;
  const int b = blockIdx.z;
  __shared__ float Bsh[SCH][16];
  __shared__ float Csh[SCH][16];
  const float beta = fmaxf(0.0f, -funkey(betak[0]));
  const int t0 = b * LL + c * SCH;
  for (int i = threadIdx.x; i < SCH * 16; i += 256) {
    int tt = i >> 4, n = i & 15;
    size_t row = (size_t)(t0 + tt) * 96;
    Bsh[tt][n] = xdb[row + 64 + n] + beta;
    Csh[tt][n] = xdb[row + 80 + n];
  }
  __syncthreads();
  float Av2[16];
#pragma unroll
  for (int n = 0; n < 16; ++n)
    Av2[n] = __builtin_amdgcn_exp2f(A_log[d * 16 + n] * LOG2E) * LOG2E;
  float h[16];
  size_t base = (((size_t)(b * NCH + c) * DI) + d) * 16;
#pragma unroll
  for (int n = 0; n < 16; ++n) h[n] = hstart[base + n];
  const float Dd = Dp[d];
  for (int tt = 0; tt < SCH; ++tt) {
    int t = t0 + tt;
    float dv = bf2f(delta[(size_t)t * DI + d]);
    float xv = bf2f(xc_bf[(size_t)t * DI + d]);
    float dx = dv * xv;
    float yv = 0.f;
#pragma unroll
    for (int n = 0; n < 16; ++n) {
      float a = __builtin_amdgcn_exp2f(-dv * Av2[n]);
      h[n] = a * h[n] + dx * Bsh[tt][n];
      yv += h[n] * Csh[tt][n];
    }
    float zv = bf2f(xz_bf[(size_t)t * (2 * DI) + DI + d]);
    float out = (yv + xv * Dd) * fsilu(zv);
    ybf[(size_t)t * DI + d] = f2bf(out);
  }
}

extern "C" void kernel_launch(void* const* d_in, const int* in_sizes, int n_in,
                              void* d_out, int out_size, void* d_ws, size_t ws_size,
                              hipStream_t stream) {
  const float* hs      = (const float*)d_in[0];
  const float* W_in    = (const float*)d_in[1];
  const float* conv_w  = (const float*)d_in[2];
  const float* conv_b  = (const float*)d_in[3];
  const float* W_x     = (const float*)d_in[4];
  const float* W_dt    = (const float*)d_in[5];
  const float* dt_bias = (const float*)d_in[6];
  const float* W_out   = (const float*)d_in[7];
  const float* A_log   = (const float*)d_in[8];
  const float* Dp      = (const float*)d_in[9];
  float* out = (float*)d_out;

  float* ws       = (float*)d_ws;
  float* xz_bfR   = ws;                                  // 4,194,304 f
  float* xcv_bfR  = xz_bfR + (size_t)TT * 2 * DI / 2;    // 2,097,152 f
  float* xdb      = xcv_bfR + (size_t)TT * DI / 2;       //   196,608 f
  float* dlt_bfR  = xdb + (size_t)TT * 96;               // 2,097,152 f
  float* betab    = dlt_bfR + (size_t)TT * DI / 2;       //        64 f
  float* hend     = betab + 64;                          // 2,097,152 f
  float* Ssum     = hend + (size_t)NB * NCH * DI * 16;   //   131,072 f
  float* hs_bfR   = Ssum + (size_t)NB * NCH * DI;        // 1,048,576 f
  float* win_bfR  = hs_bfR + (size_t)TT * DM / 2;        // 2,097,152 f
  float* wout_bfR = win_bfR + (size_t)2 * DI * DM / 2;   // 1,048,576 f
  float* wx_bfR   = wout_bfR + (size_t)DM * DI / 2;      //   131,072 f
  float* wdt_bfR  = wx_bfR + 131072;                     //    65,536 f

  u16* xz_bf   = (u16*)xz_bfR;
  u16* xcv_bf  = (u16*)xcv_bfR;
  u16* dlt_bf  = (u16*)dlt_bfR;
  u16* hs_bf   = (u16*)hs_bfR;
  u16* win_bf  = (u16*)win_bfR;
  u16* wout_bf = (u16*)wout_bfR;
  u16* wx_bf   = (u16*)wx_bfR;
  u16* wdt_bf  = (u16*)wdt_bfR;
  unsigned* betakey = (unsigned*)betab;
  u16* ybf     = (u16*)win_bfR;   // aliases win_bf (dead after GEMM1)

  dim3 blk(256);

  // 1) bf16 casts + zero xdb/out + betakey init
  cast_all<<<10816, blk, 0, stream>>>(hs, W_in, W_out, W_x, W_dt,
                                      hs_bf, win_bf, wout_bf, wx_bf, wdt_bf,
                                      xdb, out, betakey);

  // 2) xz = hs @ W_in^T  (2048x4096x1024) bf16 GLDS -> bf16 xz. 512 blocks.
  gemm_k<128, 128, 0, 1, 0, 0, 0>
      <<<dim3(4096 / 128, TT / 128), blk, 0, stream>>>(
      hs_bf, win_bf, xz_bf, TT, 2 * DI, DM, DM, DM, DM,
      nullptr, nullptr, nullptr);

  // 3) conv + silu -> xcv_bf
  conv_silu4<<<(TT * DI / 4) / 256, blk, 0, stream>>>(xz_bf, conv_w, conv_b, xcv_bf);

  // 4) x_dbl: (2048x128x2048) bf16 GLDS both, split-K=8, atomicAdd cols<96
  gemm_k<64, 128, 0, 2, 96, 0, 0>
      <<<dim3(1, TT / 64, 8), blk, 0, stream>>>(
      xcv_bf, wx_bf, xdb, TT, 128, DI, DI, DI, DI / 8,
      nullptr, nullptr, nullptr);

  // 5) delta: A = xdb cols0..63 fp32 reg-staged (lda=96), B = wdt_bf GLDS,
  //    softplus/clip -> bf16 dlt; blocks 0..63 also reduce beta-min (BMIN)
  gemm_k<64, 128, 1, 1, 0, 1, 1>
      <<<dim3(DI / 128, TT / 64), blk, 0, stream>>>(
      xdb, wdt_bf, dlt_bf, TT, DI, DTR, 96, DTR, DTR,
      dt_bias, xdb, betakey);

  // 6) chunked selective scan -> ybf
  scan_pass1<<<dim3(DI / 256, NCH, NB), blk, 0, stream>>>(
      dlt_bf, xcv_bf, xdb, A_log, betakey, hend, Ssum);
  scan_pass2<<<(NB * DI * DS) / 256, blk, 0, stream>>>(hend, Ssum, A_log);
  scan_pass3<<<dim3(DI / 256, NCH, NB), blk, 0, stream>>>(
      dlt_bf, xcv_bf, xdb, xz_bf, A_log, Dp, betakey, hend, ybf);

  // 7) out = y @ W_out^T (2048x1024x2048) bf16 GLDS both, split-K=4 atomic
  gemm_k<128, 128, 0, 2, 0, 0, 0>
      <<<dim3(DM / 128, TT / 128, 4), blk, 0, stream>>>(
      ybf, wout_bf, out, TT, DM, DI, DI, DI, DI / 4,
      nullptr, nullptr, nullptr);
}